// Round 1
// baseline (721.619 us; speedup 1.0000x reference)
//
#include <hip/hip_runtime.h>
#include <math.h>

constexpr int IN   = 512;
constexpr int HID  = 128;
constexpr int OUTD = 64;
constexpr int KC   = 20;
#define LRELU_SLOPE 0.2f

__device__ __forceinline__ float warp_sum(float v) {
#pragma unroll
  for (int o = 32; o > 0; o >>= 1) v += __shfl_xor(v, o, 64);
  return v;
}
__device__ __forceinline__ float warp_max(float v) {
#pragma unroll
  for (int o = 32; o > 0; o >>= 1) v = fmaxf(v, __shfl_xor(v, o, 64));
  return v;
}

__global__ void k_zero_int(int* p, int n) {
  int i = blockIdx.x * blockDim.x + threadIdx.x;
  if (i < n) p[i] = 0;
}

// ---------------- GEMM1: h = x @ W_gat  (M x 512) @ (512 x 128) ----------------
__global__ __launch_bounds__(256) void k_gemm1(const float* __restrict__ A,
                                               const float* __restrict__ B,
                                               float* __restrict__ C, int M) {
  __shared__ float As[32][64];   // transposed A tile
  __shared__ float Bs[32][128];
  const int tid = threadIdx.x;
  const int row0 = blockIdx.x * 64;
  const int rg = tid >> 4, cg = tid & 15;
  float acc[4][8];
#pragma unroll
  for (int i = 0; i < 4; ++i)
#pragma unroll
    for (int j = 0; j < 8; ++j) acc[i][j] = 0.f;

  for (int k0 = 0; k0 < IN; k0 += 32) {
#pragma unroll
    for (int t = 0; t < 2; ++t) {
      int idx = tid + t * 256;       // 512 float4 slots (64 rows x 8 f4)
      int r = idx >> 3;
      int c = (idx & 7) << 2;
      float4 v = make_float4(0.f, 0.f, 0.f, 0.f);
      int gr = row0 + r;
      if (gr < M) v = *(const float4*)(A + (size_t)gr * IN + k0 + c);
      As[c + 0][r] = v.x; As[c + 1][r] = v.y; As[c + 2][r] = v.z; As[c + 3][r] = v.w;
    }
#pragma unroll
    for (int t = 0; t < 4; ++t) {
      int idx = tid + t * 256;       // 1024 float4 slots (32 rows x 32 f4)
      int r = idx >> 5;
      int c = (idx & 31) << 2;
      *(float4*)(&Bs[r][c]) = *(const float4*)(B + (size_t)(k0 + r) * HID + c);
    }
    __syncthreads();
#pragma unroll
    for (int kk = 0; kk < 32; ++kk) {
      float4 a  = *(const float4*)(&As[kk][rg << 2]);
      float4 b0 = *(const float4*)(&Bs[kk][cg << 3]);
      float4 b1 = *(const float4*)(&Bs[kk][(cg << 3) + 4]);
      float av[4] = {a.x, a.y, a.z, a.w};
      float bv[8] = {b0.x, b0.y, b0.z, b0.w, b1.x, b1.y, b1.z, b1.w};
#pragma unroll
      for (int i = 0; i < 4; ++i)
#pragma unroll
        for (int j = 0; j < 8; ++j) acc[i][j] = fmaf(av[i], bv[j], acc[i][j]);
    }
    __syncthreads();
  }
#pragma unroll
  for (int i = 0; i < 4; ++i) {
    int gr = row0 + (rg << 2) + i;
    if (gr < M) {
      float4 o0 = make_float4(acc[i][0], acc[i][1], acc[i][2], acc[i][3]);
      float4 o1 = make_float4(acc[i][4], acc[i][5], acc[i][6], acc[i][7]);
      *(float4*)(C + (size_t)gr * HID + (cg << 3))     = o0;
      *(float4*)(C + (size_t)gr * HID + (cg << 3) + 4) = o1;
    }
  }
}

// ---------------- el/er: per-node dot(h, attn) ----------------
__global__ __launch_bounds__(256) void k_elr(const float* __restrict__ h,
                                             const float* __restrict__ al,
                                             const float* __restrict__ ar,
                                             float* __restrict__ el,
                                             float* __restrict__ er, int N) {
  int g = blockIdx.x * blockDim.x + threadIdx.x;
  int v = g >> 6, lane = g & 63;
  if (v >= N) return;
  float h0 = h[(size_t)v * HID + lane];
  float h1 = h[(size_t)v * HID + 64 + lane];
  float sl = h0 * al[lane] + h1 * al[64 + lane];
  float sr = h0 * ar[lane] + h1 * ar[64 + lane];
  sl = warp_sum(sl);
  sr = warp_sum(sr);
  if (lane == 0) { el[v] = sl; er[v] = sr; }
}

// ---------------- CSR build ----------------
__global__ void k_hist(const int* __restrict__ dst, int* counts, int E) {
  int i = blockIdx.x * blockDim.x + threadIdx.x;
  if (i < E) atomicAdd(&counts[dst[i]], 1);
}

__global__ __launch_bounds__(256) void k_scan1(const int* __restrict__ counts, int* bsum, int N) {
  __shared__ int s[256];
  int b = blockIdx.x, t = threadIdx.x;
  int i0 = b * 512 + t * 2;
  int v = 0;
  if (i0 < N) v += counts[i0];
  if (i0 + 1 < N) v += counts[i0 + 1];
  s[t] = v;
  __syncthreads();
  for (int off = 128; off > 0; off >>= 1) {
    if (t < off) s[t] += s[t + off];
    __syncthreads();
  }
  if (t == 0) bsum[b] = s[0];
}

__global__ __launch_bounds__(256) void k_scan2(const int* __restrict__ bsum, int* boff, int nblk) {
  __shared__ int s[256];
  int t = threadIdx.x;
  int v = (t < nblk) ? bsum[t] : 0;
  s[t] = v;
  __syncthreads();
#pragma unroll
  for (int off = 1; off < 256; off <<= 1) {
    int u = 0;
    if (t >= off) u = s[t - off];
    __syncthreads();
    s[t] += u;
    __syncthreads();
  }
  if (t < nblk) boff[t] = s[t] - v;   // exclusive
}

__global__ __launch_bounds__(256) void k_scan3(const int* __restrict__ counts,
                                               const int* __restrict__ boff,
                                               int* rowptr, int* cursor, int N) {
  __shared__ int s[256];
  int b = blockIdx.x, t = threadIdx.x;
  int i0 = b * 512 + t * 2;
  int c0 = (i0 < N) ? counts[i0] : 0;
  int c1 = (i0 + 1 < N) ? counts[i0 + 1] : 0;
  int tsum = c0 + c1;
  s[t] = tsum;
  __syncthreads();
#pragma unroll
  for (int off = 1; off < 256; off <<= 1) {
    int u = 0;
    if (t >= off) u = s[t - off];
    __syncthreads();
    s[t] += u;
    __syncthreads();
  }
  int base = boff[b] + s[t] - tsum;
  if (i0 < N)     { rowptr[i0] = base;          cursor[i0] = base; }
  if (i0 + 1 < N) { rowptr[i0 + 1] = base + c0; cursor[i0 + 1] = base + c0; }
}

__global__ void k_fill(const int* __restrict__ src, const int* __restrict__ dst,
                       int* cursor, int* colsrc, int E) {
  int i = blockIdx.x * blockDim.x + threadIdx.x;
  if (i < E) {
    int d = dst[i];
    int pos = atomicAdd(&cursor[d], 1);
    colsrc[pos] = src[i];
  }
}

// ---------------- per-node edge softmax + aggregation + elu ----------------
__global__ __launch_bounds__(256) void k_agg(const float* __restrict__ h,
                                             const float* __restrict__ el,
                                             const float* __restrict__ er,
                                             const int* __restrict__ rowptr,
                                             const int* __restrict__ counts,
                                             const int* __restrict__ colsrc,
                                             const float* __restrict__ bias,
                                             float* __restrict__ eh, int N) {
  int g = blockIdx.x * blockDim.x + threadIdx.x;
  int v = g >> 6, lane = g & 63;
  if (v >= N) return;
  int start = rowptr[v], deg = counts[v];
  float erv = er[v];

  float mx = -INFINITY;
  for (int j = lane; j < deg; j += 64) {
    int u = colsrc[start + j];
    float e = el[u] + erv;
    e = (e > 0.f) ? e : LRELU_SLOPE * e;
    mx = fmaxf(mx, e);
  }
  mx = warp_max(mx);

  float a0 = 0.f, a1 = 0.f, den = 0.f;
  for (int j = 0; j < deg; ++j) {
    int u = colsrc[start + j];
    float e = el[u] + erv;
    e = (e > 0.f) ? e : LRELU_SLOPE * e;
    float w = expf(e - mx);
    den += w;
    a0 = fmaf(w, h[(size_t)u * HID + lane], a0);
    a1 = fmaf(w, h[(size_t)u * HID + 64 + lane], a1);
  }
  float inv = 1.f / den;
  float x0 = a0 * inv + bias[lane];
  float x1 = a1 * inv + bias[64 + lane];
  eh[(size_t)v * HID + lane]      = (x0 > 0.f) ? x0 : expm1f(x0);
  eh[(size_t)v * HID + 64 + lane] = (x1 > 0.f) ? x1 : expm1f(x1);
}

// ---------------- GEMM2: embed = eh @ W_enc  (M x 128) @ (128 x 64) ----------------
__global__ __launch_bounds__(256) void k_gemm2(const float* __restrict__ A,
                                               const float* __restrict__ B,
                                               float* __restrict__ C, int M) {
  __shared__ float As[HID][64];
  __shared__ float Bs[HID][OUTD];
  const int tid = threadIdx.x;
  const int row0 = blockIdx.x * 64;
  const int rg = tid >> 4, cg = tid & 15;
#pragma unroll
  for (int t = 0; t < 8; ++t) {
    int idx = tid + t * 256;          // 2048 f4 (64 rows x 32 f4)
    int r = idx >> 5;
    int c = (idx & 31) << 2;
    float4 v = make_float4(0.f, 0.f, 0.f, 0.f);
    int gr = row0 + r;
    if (gr < M) v = *(const float4*)(A + (size_t)gr * HID + c);
    As[c + 0][r] = v.x; As[c + 1][r] = v.y; As[c + 2][r] = v.z; As[c + 3][r] = v.w;
  }
#pragma unroll
  for (int t = 0; t < 8; ++t) {
    int idx = tid + t * 256;          // 2048 f4 (128 rows x 16 f4)
    int r = idx >> 4;
    int c = (idx & 15) << 2;
    *(float4*)(&Bs[r][c]) = *(const float4*)(B + (size_t)r * OUTD + c);
  }
  __syncthreads();
  float acc[4][4];
#pragma unroll
  for (int i = 0; i < 4; ++i)
#pragma unroll
    for (int j = 0; j < 4; ++j) acc[i][j] = 0.f;
#pragma unroll 4
  for (int k = 0; k < HID; ++k) {
    float4 a = *(const float4*)(&As[k][rg << 2]);
    float4 b = *(const float4*)(&Bs[k][cg << 2]);
    float av[4] = {a.x, a.y, a.z, a.w};
    float bv[4] = {b.x, b.y, b.z, b.w};
#pragma unroll
    for (int i = 0; i < 4; ++i)
#pragma unroll
      for (int j = 0; j < 4; ++j) acc[i][j] = fmaf(av[i], bv[j], acc[i][j]);
  }
#pragma unroll
  for (int i = 0; i < 4; ++i) {
    int gr = row0 + (rg << 2) + i;
    if (gr < M) {
      float4 o = make_float4(acc[i][0], acc[i][1], acc[i][2], acc[i][3]);
      *(float4*)(C + (size_t)gr * OUTD + (cg << 2)) = o;
    }
  }
}

// ---------------- GEMM3: pred = elu(embed @ W_dec)  (M x 64) @ (64 x 512) ----------------
__global__ __launch_bounds__(256) void k_gemm3(const float* __restrict__ A,
                                               const float* __restrict__ B,
                                               float* __restrict__ C, int M) {
  __shared__ float As[OUTD][64];
  __shared__ float Bs[OUTD][128];
  const int tid = threadIdx.x;
  const int row0 = blockIdx.x * 64;
  const int cb = blockIdx.y * 128;
  const int rg = tid >> 4, cg = tid & 15;
#pragma unroll
  for (int t = 0; t < 4; ++t) {
    int idx = tid + t * 256;          // 1024 f4 (64 rows x 16 f4)
    int r = idx >> 4;
    int c = (idx & 15) << 2;
    float4 v = make_float4(0.f, 0.f, 0.f, 0.f);
    int gr = row0 + r;
    if (gr < M) v = *(const float4*)(A + (size_t)gr * OUTD + c);
    As[c + 0][r] = v.x; As[c + 1][r] = v.y; As[c + 2][r] = v.z; As[c + 3][r] = v.w;
  }
#pragma unroll
  for (int t = 0; t < 8; ++t) {
    int idx = tid + t * 256;          // 2048 f4 (64 rows x 32 f4)
    int r = idx >> 5;
    int c = (idx & 31) << 2;
    *(float4*)(&Bs[r][c]) = *(const float4*)(B + (size_t)r * IN + cb + c);
  }
  __syncthreads();
  float acc[4][8];
#pragma unroll
  for (int i = 0; i < 4; ++i)
#pragma unroll
    for (int j = 0; j < 8; ++j) acc[i][j] = 0.f;
#pragma unroll 4
  for (int k = 0; k < OUTD; ++k) {
    float4 a  = *(const float4*)(&As[k][rg << 2]);
    float4 b0 = *(const float4*)(&Bs[k][cg << 3]);
    float4 b1 = *(const float4*)(&Bs[k][(cg << 3) + 4]);
    float av[4] = {a.x, a.y, a.z, a.w};
    float bv[8] = {b0.x, b0.y, b0.z, b0.w, b1.x, b1.y, b1.z, b1.w};
#pragma unroll
    for (int i = 0; i < 4; ++i)
#pragma unroll
      for (int j = 0; j < 8; ++j) acc[i][j] = fmaf(av[i], bv[j], acc[i][j]);
  }
#pragma unroll
  for (int i = 0; i < 4; ++i) {
    int gr = row0 + (rg << 2) + i;
    if (gr < M) {
      float o[8];
#pragma unroll
      for (int j = 0; j < 8; ++j) {
        float x = acc[i][j];
        o[j] = (x > 0.f) ? x : expm1f(x);
      }
      *(float4*)(C + (size_t)gr * IN + cb + (cg << 3))     = make_float4(o[0], o[1], o[2], o[3]);
      *(float4*)(C + (size_t)gr * IN + cb + (cg << 3) + 4) = make_float4(o[4], o[5], o[6], o[7]);
    }
  }
}

// ---------------- DEC soft assignment q ----------------
__global__ __launch_bounds__(256) void k_q(const float* __restrict__ embed,
                                           const float* __restrict__ cent,
                                           float* __restrict__ q, int N) {
  __shared__ float Cs[KC * OUTD];
  int tid = threadIdx.x;
  for (int t = tid; t < KC * OUTD; t += 256) Cs[t] = cent[t];
  __syncthreads();
  int g = blockIdx.x * blockDim.x + tid;
  int v = g >> 6, lane = g & 63;
  if (v >= N) return;
  float e = embed[(size_t)v * OUTD + lane];
  float mine = 0.f, qs = 0.f;
  for (int k = 0; k < KC; ++k) {
    float d = e - Cs[k * OUTD + lane];
    float s = warp_sum(d * d);
    float qk = 1.f / (1.f + s + 1e-8f);
    qs += qk;
    if (lane == k) mine = qk;
  }
  if (lane < KC) q[(size_t)v * KC + lane] = mine / qs;
}

extern "C" void kernel_launch(void* const* d_in, const int* in_sizes, int n_in,
                              void* d_out, int out_size, void* d_ws, size_t ws_size,
                              hipStream_t stream) {
  const float* x      = (const float*)d_in[0];
  const float* W_gat  = (const float*)d_in[1];
  const float* attn_l = (const float*)d_in[2];
  const float* attn_r = (const float*)d_in[3];
  const float* bias   = (const float*)d_in[4];
  const float* W_enc  = (const float*)d_in[5];
  const float* W_dec  = (const float*)d_in[6];
  const float* cent   = (const float*)d_in[7];
  const int*   src    = (const int*)d_in[8];
  const int*   dst    = (const int*)d_in[9];

  const int N = in_sizes[0] / IN;
  const int E = in_sizes[8];

  float* out   = (float*)d_out;
  float* embed = out;                            // N x 64
  float* pred  = out + (size_t)N * OUTD;         // N x 512
  float* qout  = pred + (size_t)N * IN;          // N x 20

  char* w = (char*)d_ws;
  float* h  = (float*)w;  w += sizeof(float) * (size_t)N * HID;
  float* eh = (float*)w;  w += sizeof(float) * (size_t)N * HID;
  float* el = (float*)w;  w += sizeof(float) * (size_t)N;
  float* er = (float*)w;  w += sizeof(float) * (size_t)N;
  int* counts = (int*)w;  w += sizeof(int) * (size_t)N;
  int* rowptr = (int*)w;  w += sizeof(int) * (size_t)(N + 1);
  int* cursor = (int*)w;  w += sizeof(int) * (size_t)N;
  int* colsrc = (int*)w;  w += sizeof(int) * (size_t)E;
  int* bsum   = (int*)w;  w += sizeof(int) * 256;
  int* boff   = (int*)w;  w += sizeof(int) * 256;

  const int nblk_scan = (N + 511) / 512;   // 196 for N=100000 (<=256)

  hipLaunchKernelGGL(k_zero_int, dim3((N + 255) / 256), dim3(256), 0, stream, counts, N);
  hipLaunchKernelGGL(k_gemm1, dim3((N + 63) / 64), dim3(256), 0, stream, x, W_gat, h, N);
  hipLaunchKernelGGL(k_elr, dim3(((size_t)N * 64 + 255) / 256), dim3(256), 0, stream,
                     h, attn_l, attn_r, el, er, N);
  hipLaunchKernelGGL(k_hist, dim3((E + 255) / 256), dim3(256), 0, stream, dst, counts, E);
  hipLaunchKernelGGL(k_scan1, dim3(nblk_scan), dim3(256), 0, stream, counts, bsum, N);
  hipLaunchKernelGGL(k_scan2, dim3(1), dim3(256), 0, stream, bsum, boff, nblk_scan);
  hipLaunchKernelGGL(k_scan3, dim3(nblk_scan), dim3(256), 0, stream, counts, boff, rowptr, cursor, N);
  hipLaunchKernelGGL(k_fill, dim3((E + 255) / 256), dim3(256), 0, stream, src, dst, cursor, colsrc, E);
  hipLaunchKernelGGL(k_agg, dim3(((size_t)N * 64 + 255) / 256), dim3(256), 0, stream,
                     h, el, er, rowptr, counts, colsrc, bias, eh, N);
  hipLaunchKernelGGL(k_gemm2, dim3((N + 63) / 64), dim3(256), 0, stream, eh, W_enc, embed, N);
  hipLaunchKernelGGL(k_gemm3, dim3((N + 63) / 64, IN / 128), dim3(256), 0, stream, embed, W_dec, pred, N);
  hipLaunchKernelGGL(k_q, dim3(((size_t)N * 64 + 255) / 256), dim3(256), 0, stream, embed, cent, qout, N);
}

// Round 2
// 504.574 us; speedup vs baseline: 1.4302x; 1.4302x over previous
//
#include <hip/hip_runtime.h>
#include <math.h>

constexpr int IN   = 512;
constexpr int HID  = 128;
constexpr int OUTD = 64;
constexpr int KC   = 20;
#define LRELU_SLOPE 0.2f

typedef _Float16 half8 __attribute__((ext_vector_type(8)));
typedef float f32x16 __attribute__((ext_vector_type(16)));

__device__ __forceinline__ float warp_sum(float v) {
#pragma unroll
  for (int o = 32; o > 0; o >>= 1) v += __shfl_xor(v, o, 64);
  return v;
}

__global__ void k_zero_int(int* p, int n) {
  int i = blockIdx.x * blockDim.x + threadIdx.x;
  if (i < n) p[i] = 0;
}

// ---------------- prep: transpose+convert weights to f16 [col][K] ----------------
__global__ __launch_bounds__(256) void k_prepB(const float* __restrict__ Wg,
                                               const float* __restrict__ We,
                                               const float* __restrict__ Wd,
                                               _Float16* Bg, _Float16* Be, _Float16* Bd) {
  int i = blockIdx.x * 256 + threadIdx.x;
  if (i < HID * IN) {                 // Bg[c][k] = Wg[k][c], c<128,k<512
    int c = i >> 9, k = i & 511;
    Bg[i] = (_Float16)Wg[(size_t)k * HID + c];
    return;
  }
  i -= HID * IN;
  if (i < OUTD * HID) {               // Be[c][k] = We[k][c], c<64,k<128
    int c = i >> 7, k = i & 127;
    Be[i] = (_Float16)We[(size_t)k * OUTD + c];
    return;
  }
  i -= OUTD * HID;
  if (i < IN * OUTD) {                // Bd[c][k] = Wd[k][c], c<512,k<64
    int c = i >> 6, k = i & 63;
    Bd[i] = (_Float16)Wd[(size_t)k * IN + c];
  }
}

// ---------------- GEMM1: h(f16) = x @ W_gat   (M x 512)(512 x 128), MFMA ----------------
// block 128x128, BK=64, 4 waves in 2x2, wave tile 64x64 (2x2 of 32x32x16)
__global__ __launch_bounds__(256) void k_gemm1(const float* __restrict__ A,
                                               const _Float16* __restrict__ Bt,
                                               _Float16* __restrict__ H, int M) {
  __shared__ _Float16 As[128 * 72];
  __shared__ _Float16 Bs[128 * 72];
  const int tid = threadIdx.x;
  const int lane = tid & 63, wid = tid >> 6;
  const int wrow = (wid >> 1) * 64, wcol = (wid & 1) * 64;
  const int row0 = blockIdx.x * 128;
  const int l31 = lane & 31, lhi = lane >> 5;

  f32x16 acc[2][2] = {};

  for (int k0 = 0; k0 < IN; k0 += 64) {
#pragma unroll
    for (int c = 0; c < 4; ++c) {       // A: 128 rows x 8 k-octets
      int idx = tid + c * 256;
      int r = idx >> 3, ko = idx & 7;
      int gr = row0 + r;
      float4 v0 = make_float4(0.f, 0.f, 0.f, 0.f), v1 = v0;
      if (gr < M) {
        const float* p = A + (size_t)gr * IN + k0 + ko * 8;
        v0 = *(const float4*)p;
        v1 = *(const float4*)(p + 4);
      }
      half8 hv;
      hv[0] = (_Float16)v0.x; hv[1] = (_Float16)v0.y; hv[2] = (_Float16)v0.z; hv[3] = (_Float16)v0.w;
      hv[4] = (_Float16)v1.x; hv[5] = (_Float16)v1.y; hv[6] = (_Float16)v1.z; hv[7] = (_Float16)v1.w;
      *(half8*)(&As[r * 72 + ko * 8]) = hv;
    }
#pragma unroll
    for (int c = 0; c < 4; ++c) {       // B: 128 cols x 8 k-octets (already f16, [col][K])
      int idx = tid + c * 256;
      int col = idx >> 3, ko = idx & 7;
      *(half8*)(&Bs[col * 72 + ko * 8]) = *(const half8*)(Bt + (size_t)col * IN + k0 + ko * 8);
    }
    __syncthreads();
#pragma unroll
    for (int ks = 0; ks < 4; ++ks) {
      half8 a0 = *(half8*)(&As[(wrow + l31) * 72      + ks * 16 + lhi * 8]);
      half8 a1 = *(half8*)(&As[(wrow + 32 + l31) * 72 + ks * 16 + lhi * 8]);
      half8 b0 = *(half8*)(&Bs[(wcol + l31) * 72      + ks * 16 + lhi * 8]);
      half8 b1 = *(half8*)(&Bs[(wcol + 32 + l31) * 72 + ks * 16 + lhi * 8]);
      acc[0][0] = __builtin_amdgcn_mfma_f32_32x32x16_f16(a0, b0, acc[0][0], 0, 0, 0);
      acc[0][1] = __builtin_amdgcn_mfma_f32_32x32x16_f16(a0, b1, acc[0][1], 0, 0, 0);
      acc[1][0] = __builtin_amdgcn_mfma_f32_32x32x16_f16(a1, b0, acc[1][0], 0, 0, 0);
      acc[1][1] = __builtin_amdgcn_mfma_f32_32x32x16_f16(a1, b1, acc[1][1], 0, 0, 0);
    }
    __syncthreads();
  }
#pragma unroll
  for (int mr = 0; mr < 2; ++mr)
#pragma unroll
    for (int r = 0; r < 16; ++r) {
      int row = row0 + wrow + mr * 32 + (r & 3) + 8 * (r >> 2) + 4 * lhi;
      if (row < M) {
#pragma unroll
        for (int nr = 0; nr < 2; ++nr)
          H[(size_t)row * HID + wcol + nr * 32 + l31] = (_Float16)acc[mr][nr][r];
      }
    }
}

// ---------------- el/er from f16 h ----------------
__global__ __launch_bounds__(256) void k_elr(const _Float16* __restrict__ h,
                                             const float* __restrict__ al,
                                             const float* __restrict__ ar,
                                             float* __restrict__ el,
                                             float* __restrict__ er, int N) {
  int g = blockIdx.x * blockDim.x + threadIdx.x;
  int v = g >> 6, lane = g & 63;
  if (v >= N) return;
  float h0 = (float)h[(size_t)v * HID + lane];
  float h1 = (float)h[(size_t)v * HID + 64 + lane];
  float sl = h0 * al[lane] + h1 * al[64 + lane];
  float sr = h0 * ar[lane] + h1 * ar[64 + lane];
  sl = warp_sum(sl);
  sr = warp_sum(sr);
  if (lane == 0) { el[v] = sl; er[v] = sr; }
}

// ---------------- CSR build ----------------
__global__ void k_hist(const int* __restrict__ dst, int* counts, int E) {
  int i = blockIdx.x * blockDim.x + threadIdx.x;
  if (i < E) atomicAdd(&counts[dst[i]], 1);
}

__global__ __launch_bounds__(256) void k_scan1(const int* __restrict__ counts, int* bsum, int N) {
  __shared__ int s[256];
  int b = blockIdx.x, t = threadIdx.x;
  int i0 = b * 512 + t * 2;
  int v = 0;
  if (i0 < N) v += counts[i0];
  if (i0 + 1 < N) v += counts[i0 + 1];
  s[t] = v;
  __syncthreads();
  for (int off = 128; off > 0; off >>= 1) {
    if (t < off) s[t] += s[t + off];
    __syncthreads();
  }
  if (t == 0) bsum[b] = s[0];
}

__global__ __launch_bounds__(256) void k_scan2(const int* __restrict__ bsum, int* boff, int nblk) {
  __shared__ int s[256];
  int t = threadIdx.x;
  int v = (t < nblk) ? bsum[t] : 0;
  s[t] = v;
  __syncthreads();
#pragma unroll
  for (int off = 1; off < 256; off <<= 1) {
    int u = 0;
    if (t >= off) u = s[t - off];
    __syncthreads();
    s[t] += u;
    __syncthreads();
  }
  if (t < nblk) boff[t] = s[t] - v;
}

__global__ __launch_bounds__(256) void k_scan3(const int* __restrict__ counts,
                                               const int* __restrict__ boff,
                                               int* rowptr, int* cursor, int N) {
  __shared__ int s[256];
  int b = blockIdx.x, t = threadIdx.x;
  int i0 = b * 512 + t * 2;
  int c0 = (i0 < N) ? counts[i0] : 0;
  int c1 = (i0 + 1 < N) ? counts[i0 + 1] : 0;
  int tsum = c0 + c1;
  s[t] = tsum;
  __syncthreads();
#pragma unroll
  for (int off = 1; off < 256; off <<= 1) {
    int u = 0;
    if (t >= off) u = s[t - off];
    __syncthreads();
    s[t] += u;
    __syncthreads();
  }
  int base = boff[b] + s[t] - tsum;
  if (i0 < N)     { rowptr[i0] = base;          cursor[i0] = base; }
  if (i0 + 1 < N) { rowptr[i0 + 1] = base + c0; cursor[i0 + 1] = base + c0; }
}

__global__ void k_fill(const int* __restrict__ src, const int* __restrict__ dst,
                       int* cursor, int* colsrc, int E) {
  int i = blockIdx.x * blockDim.x + threadIdx.x;
  if (i < E) {
    int d = dst[i];
    int pos = atomicAdd(&cursor[d], 1);
    colsrc[pos] = src[i];
  }
}

// ---------------- single-pass edge softmax + aggregation + elu -> eh(f16) ----------------
__global__ __launch_bounds__(256) void k_agg(const _Float16* __restrict__ h,
                                             const float* __restrict__ el,
                                             const float* __restrict__ er,
                                             const int* __restrict__ rowptr,
                                             const int* __restrict__ counts,
                                             const int* __restrict__ colsrc,
                                             const float* __restrict__ bias,
                                             _Float16* __restrict__ eh, int N) {
  int g = blockIdx.x * blockDim.x + threadIdx.x;
  int v = g >> 6, lane = g & 63;
  if (v >= N) return;
  int start = rowptr[v], deg = counts[v];
  float erv = er[v];

  float a0 = 0.f, a1 = 0.f, den = 0.f;
  for (int j = 0; j < deg; ++j) {
    int u = colsrc[start + j];
    float e = el[u] + erv;
    e = (e > 0.f) ? e : LRELU_SLOPE * e;
    float w = expf(e);                  // softmax shift-invariant; e bounded (~<=10)
    den += w;
    a0 = fmaf(w, (float)h[(size_t)u * HID + lane], a0);
    a1 = fmaf(w, (float)h[(size_t)u * HID + 64 + lane], a1);
  }
  float inv = 1.f / den;
  float x0 = a0 * inv + bias[lane];
  float x1 = a1 * inv + bias[64 + lane];
  eh[(size_t)v * HID + lane]      = (_Float16)((x0 > 0.f) ? x0 : expm1f(x0));
  eh[(size_t)v * HID + 64 + lane] = (_Float16)((x1 > 0.f) ? x1 : expm1f(x1));
}

// ---------------- GEMM2: embed = eh @ W_enc  (M x 128)(128 x 64), MFMA ----------------
// block 128x64, BK=128 (single step), 4 waves 2x2, wave 64x32
__global__ __launch_bounds__(256) void k_gemm2(const _Float16* __restrict__ A,
                                               const _Float16* __restrict__ Bt,
                                               float* __restrict__ C,
                                               _Float16* __restrict__ C16, int M) {
  __shared__ _Float16 As[128 * 136];
  __shared__ _Float16 Bs[64 * 136];
  const int tid = threadIdx.x;
  const int lane = tid & 63, wid = tid >> 6;
  const int wrow = (wid >> 1) * 64, wcol = (wid & 1) * 32;
  const int row0 = blockIdx.x * 128;
  const int l31 = lane & 31, lhi = lane >> 5;

#pragma unroll
  for (int c = 0; c < 8; ++c) {         // A: 128 rows x 16 octets
    int idx = tid + c * 256;
    int r = idx >> 4, ko = idx & 15;
    int gr = row0 + r;
    half8 hv = {};
    if (gr < M) hv = *(const half8*)(A + (size_t)gr * HID + ko * 8);
    *(half8*)(&As[r * 136 + ko * 8]) = hv;
  }
#pragma unroll
  for (int c = 0; c < 4; ++c) {         // B: 64 cols x 16 octets
    int idx = tid + c * 256;
    int col = idx >> 4, ko = idx & 15;
    *(half8*)(&Bs[col * 136 + ko * 8]) = *(const half8*)(Bt + (size_t)col * HID + ko * 8);
  }
  __syncthreads();

  f32x16 acc[2] = {};
#pragma unroll
  for (int ks = 0; ks < 8; ++ks) {
    half8 a0 = *(half8*)(&As[(wrow + l31) * 136      + ks * 16 + lhi * 8]);
    half8 a1 = *(half8*)(&As[(wrow + 32 + l31) * 136 + ks * 16 + lhi * 8]);
    half8 b0 = *(half8*)(&Bs[(wcol + l31) * 136      + ks * 16 + lhi * 8]);
    acc[0] = __builtin_amdgcn_mfma_f32_32x32x16_f16(a0, b0, acc[0], 0, 0, 0);
    acc[1] = __builtin_amdgcn_mfma_f32_32x32x16_f16(a1, b0, acc[1], 0, 0, 0);
  }
#pragma unroll
  for (int mr = 0; mr < 2; ++mr)
#pragma unroll
    for (int r = 0; r < 16; ++r) {
      int row = row0 + wrow + mr * 32 + (r & 3) + 8 * (r >> 2) + 4 * lhi;
      if (row < M) {
        int col = wcol + l31;
        float x = acc[mr][r];
        C[(size_t)row * OUTD + col] = x;
        C16[(size_t)row * OUTD + col] = (_Float16)x;
      }
    }
}

// ---------------- GEMM3: pred = elu(embed @ W_dec)  (M x 64)(64 x 512), MFMA ----------------
// block 128x512, BK=64 (single step), 8 waves 2x4, wave 64x128
__global__ __launch_bounds__(512) void k_gemm3(const _Float16* __restrict__ A,
                                               const _Float16* __restrict__ Bt,
                                               float* __restrict__ C, int M) {
  __shared__ _Float16 As[128 * 72];
  __shared__ _Float16 Bs[512 * 72];
  const int tid = threadIdx.x;
  const int lane = tid & 63, wid = tid >> 6;
  const int wrow = (wid >> 2) * 64, wcol = (wid & 3) * 128;
  const int row0 = blockIdx.x * 128;
  const int l31 = lane & 31, lhi = lane >> 5;

#pragma unroll
  for (int c = 0; c < 2; ++c) {         // A: 128 rows x 8 octets
    int idx = tid + c * 512;
    int r = idx >> 3, ko = idx & 7;
    int gr = row0 + r;
    half8 hv = {};
    if (gr < M) hv = *(const half8*)(A + (size_t)gr * OUTD + ko * 8);
    *(half8*)(&As[r * 72 + ko * 8]) = hv;
  }
#pragma unroll
  for (int c = 0; c < 8; ++c) {         // B: 512 cols x 8 octets
    int idx = tid + c * 512;
    int col = idx >> 3, ko = idx & 7;
    *(half8*)(&Bs[col * 72 + ko * 8]) = *(const half8*)(Bt + (size_t)col * OUTD + ko * 8);
  }
  __syncthreads();

  f32x16 acc[2][4] = {};
#pragma unroll
  for (int ks = 0; ks < 4; ++ks) {
    half8 a0 = *(half8*)(&As[(wrow + l31) * 72      + ks * 16 + lhi * 8]);
    half8 a1 = *(half8*)(&As[(wrow + 32 + l31) * 72 + ks * 16 + lhi * 8]);
#pragma unroll
    for (int nr = 0; nr < 4; ++nr) {
      half8 b = *(half8*)(&Bs[(wcol + nr * 32 + l31) * 72 + ks * 16 + lhi * 8]);
      acc[0][nr] = __builtin_amdgcn_mfma_f32_32x32x16_f16(a0, b, acc[0][nr], 0, 0, 0);
      acc[1][nr] = __builtin_amdgcn_mfma_f32_32x32x16_f16(a1, b, acc[1][nr], 0, 0, 0);
    }
  }
#pragma unroll
  for (int mr = 0; mr < 2; ++mr)
#pragma unroll
    for (int r = 0; r < 16; ++r) {
      int row = row0 + wrow + mr * 32 + (r & 3) + 8 * (r >> 2) + 4 * lhi;
      if (row < M) {
#pragma unroll
        for (int nr = 0; nr < 4; ++nr) {
          float x = acc[mr][nr][r];
          C[(size_t)row * IN + wcol + nr * 32 + l31] = (x > 0.f) ? x : expm1f(x);
        }
      }
    }
}

// ---------------- DEC soft assignment q ----------------
__global__ __launch_bounds__(256) void k_q(const float* __restrict__ embed,
                                           const float* __restrict__ cent,
                                           float* __restrict__ q, int N) {
  __shared__ float Cs[KC * OUTD];
  int tid = threadIdx.x;
  for (int t = tid; t < KC * OUTD; t += 256) Cs[t] = cent[t];
  __syncthreads();
  int g = blockIdx.x * blockDim.x + tid;
  int v = g >> 6, lane = g & 63;
  if (v >= N) return;
  float e = embed[(size_t)v * OUTD + lane];
  float mine = 0.f, qs = 0.f;
  for (int k = 0; k < KC; ++k) {
    float d = e - Cs[k * OUTD + lane];
    float s = warp_sum(d * d);
    float qk = 1.f / (1.f + s + 1e-8f);
    qs += qk;
    if (lane == k) mine = qk;
  }
  if (lane < KC) q[(size_t)v * KC + lane] = mine / qs;
}

static inline size_t align16(size_t x) { return (x + 15) & ~(size_t)15; }

extern "C" void kernel_launch(void* const* d_in, const int* in_sizes, int n_in,
                              void* d_out, int out_size, void* d_ws, size_t ws_size,
                              hipStream_t stream) {
  const float* x      = (const float*)d_in[0];
  const float* W_gat  = (const float*)d_in[1];
  const float* attn_l = (const float*)d_in[2];
  const float* attn_r = (const float*)d_in[3];
  const float* bias   = (const float*)d_in[4];
  const float* W_enc  = (const float*)d_in[5];
  const float* W_dec  = (const float*)d_in[6];
  const float* cent   = (const float*)d_in[7];
  const int*   src    = (const int*)d_in[8];
  const int*   dst    = (const int*)d_in[9];

  const int N = in_sizes[0] / IN;
  const int E = in_sizes[8];

  float* out   = (float*)d_out;
  float* embed = out;                            // N x 64
  float* pred  = out + (size_t)N * OUTD;         // N x 512
  float* qout  = pred + (size_t)N * IN;          // N x 20

  char* w = (char*)d_ws;
  size_t off = 0;
  _Float16* h16   = (_Float16*)(w + off); off = align16(off + sizeof(_Float16) * (size_t)N * HID);
  _Float16* eh16  = (_Float16*)(w + off); off = align16(off + sizeof(_Float16) * (size_t)N * HID);
  _Float16* emb16 = (_Float16*)(w + off); off = align16(off + sizeof(_Float16) * (size_t)N * OUTD);
  float* el       = (float*)(w + off);    off = align16(off + sizeof(float) * (size_t)N);
  float* er       = (float*)(w + off);    off = align16(off + sizeof(float) * (size_t)N);
  _Float16* Bt_g  = (_Float16*)(w + off); off = align16(off + sizeof(_Float16) * HID * IN);
  _Float16* Bt_e  = (_Float16*)(w + off); off = align16(off + sizeof(_Float16) * OUTD * HID);
  _Float16* Bt_d  = (_Float16*)(w + off); off = align16(off + sizeof(_Float16) * IN * OUTD);
  int* counts     = (int*)(w + off);      off = align16(off + sizeof(int) * (size_t)N);
  int* rowptr     = (int*)(w + off);      off = align16(off + sizeof(int) * (size_t)(N + 1));
  int* cursor     = (int*)(w + off);      off = align16(off + sizeof(int) * (size_t)N);
  int* colsrc     = (int*)(w + off);      off = align16(off + sizeof(int) * (size_t)E);
  int* bsum       = (int*)(w + off);      off = align16(off + sizeof(int) * 256);
  int* boff       = (int*)(w + off);      off = align16(off + sizeof(int) * 256);

  const int nblk_scan = (N + 511) / 512;
  const int prep_elems = HID * IN + OUTD * HID + IN * OUTD;

  hipLaunchKernelGGL(k_prepB, dim3((prep_elems + 255) / 256), dim3(256), 0, stream,
                     W_gat, W_enc, W_dec, Bt_g, Bt_e, Bt_d);
  hipLaunchKernelGGL(k_zero_int, dim3((N + 255) / 256), dim3(256), 0, stream, counts, N);
  hipLaunchKernelGGL(k_gemm1, dim3((N + 127) / 128), dim3(256), 0, stream, x, Bt_g, h16, N);
  hipLaunchKernelGGL(k_elr, dim3(((size_t)N * 64 + 255) / 256), dim3(256), 0, stream,
                     h16, attn_l, attn_r, el, er, N);
  hipLaunchKernelGGL(k_hist, dim3((E + 255) / 256), dim3(256), 0, stream, dst, counts, E);
  hipLaunchKernelGGL(k_scan1, dim3(nblk_scan), dim3(256), 0, stream, counts, bsum, N);
  hipLaunchKernelGGL(k_scan2, dim3(1), dim3(256), 0, stream, bsum, boff, nblk_scan);
  hipLaunchKernelGGL(k_scan3, dim3(nblk_scan), dim3(256), 0, stream, counts, boff, rowptr, cursor, N);
  hipLaunchKernelGGL(k_fill, dim3((E + 255) / 256), dim3(256), 0, stream, src, dst, cursor, colsrc, E);
  hipLaunchKernelGGL(k_agg, dim3(((size_t)N * 64 + 255) / 256), dim3(256), 0, stream,
                     h16, el, er, rowptr, counts, colsrc, bias, eh16, N);
  hipLaunchKernelGGL(k_gemm2, dim3((N + 127) / 128), dim3(256), 0, stream, eh16, Bt_e, embed, emb16, N);
  hipLaunchKernelGGL(k_gemm3, dim3((N + 127) / 128), dim3(512), 0, stream, emb16, Bt_d, pred, N);
  hipLaunchKernelGGL(k_q, dim3(((size_t)N * 64 + 255) / 256), dim3(256), 0, stream, embed, cent, qout, N);
}

// Round 3
// 391.679 us; speedup vs baseline: 1.8424x; 1.2882x over previous
//
#include <hip/hip_runtime.h>
#include <math.h>

constexpr int IN   = 512;
constexpr int HID  = 128;
constexpr int OUTD = 64;
constexpr int KC   = 20;
#define LRELU_SLOPE 0.2f

typedef _Float16 half8 __attribute__((ext_vector_type(8)));
typedef float f32x16 __attribute__((ext_vector_type(16)));

__device__ __forceinline__ float warp_sum(float v) {
#pragma unroll
  for (int o = 32; o > 0; o >>= 1) v += __shfl_xor(v, o, 64);
  return v;
}

__global__ void k_zero_int(int* p, int n) {
  int i = blockIdx.x * blockDim.x + threadIdx.x;
  if (i < n) p[i] = 0;
}

// ---------------- prep: transpose+convert weights to f16 [col][K] ----------------
__global__ __launch_bounds__(256) void k_prepB(const float* __restrict__ Wg,
                                               const float* __restrict__ We,
                                               const float* __restrict__ Wd,
                                               _Float16* Bg, _Float16* Be, _Float16* Bd) {
  int i = blockIdx.x * 256 + threadIdx.x;
  if (i < HID * IN) {                 // Bg[c][k] = Wg[k][c], c<128,k<512
    int c = i >> 9, k = i & 511;
    Bg[i] = (_Float16)Wg[(size_t)k * HID + c];
    return;
  }
  i -= HID * IN;
  if (i < OUTD * HID) {               // Be[c][k] = We[k][c], c<64,k<128
    int c = i >> 7, k = i & 127;
    Be[i] = (_Float16)We[(size_t)k * OUTD + c];
    return;
  }
  i -= OUTD * HID;
  if (i < IN * OUTD) {                // Bd[c][k] = Wd[k][c], c<512,k<64
    int c = i >> 6, k = i & 63;
    Bd[i] = (_Float16)Wd[(size_t)k * IN + c];
  }
}

// ---------------- GEMM1: h(f16) = x @ W_gat   (M x 512)(512 x 128), MFMA ----------------
// block 128x128, BK=64, 4 waves in 2x2, wave tile 64x64 (2x2 of 32x32x16)
__global__ __launch_bounds__(256) void k_gemm1(const float* __restrict__ A,
                                               const _Float16* __restrict__ Bt,
                                               _Float16* __restrict__ H, int M) {
  __shared__ _Float16 As[128 * 72];
  __shared__ _Float16 Bs[128 * 72];
  const int tid = threadIdx.x;
  const int lane = tid & 63, wid = tid >> 6;
  const int wrow = (wid >> 1) * 64, wcol = (wid & 1) * 64;
  const int row0 = blockIdx.x * 128;
  const int l31 = lane & 31, lhi = lane >> 5;

  f32x16 acc[2][2] = {};

  for (int k0 = 0; k0 < IN; k0 += 64) {
#pragma unroll
    for (int c = 0; c < 4; ++c) {       // A: 128 rows x 8 k-octets
      int idx = tid + c * 256;
      int r = idx >> 3, ko = idx & 7;
      int gr = row0 + r;
      float4 v0 = make_float4(0.f, 0.f, 0.f, 0.f), v1 = v0;
      if (gr < M) {
        const float* p = A + (size_t)gr * IN + k0 + ko * 8;
        v0 = *(const float4*)p;
        v1 = *(const float4*)(p + 4);
      }
      half8 hv;
      hv[0] = (_Float16)v0.x; hv[1] = (_Float16)v0.y; hv[2] = (_Float16)v0.z; hv[3] = (_Float16)v0.w;
      hv[4] = (_Float16)v1.x; hv[5] = (_Float16)v1.y; hv[6] = (_Float16)v1.z; hv[7] = (_Float16)v1.w;
      *(half8*)(&As[r * 72 + ko * 8]) = hv;
    }
#pragma unroll
    for (int c = 0; c < 4; ++c) {       // B: 128 cols x 8 k-octets (already f16, [col][K])
      int idx = tid + c * 256;
      int col = idx >> 3, ko = idx & 7;
      *(half8*)(&Bs[col * 72 + ko * 8]) = *(const half8*)(Bt + (size_t)col * IN + k0 + ko * 8);
    }
    __syncthreads();
#pragma unroll
    for (int ks = 0; ks < 4; ++ks) {
      half8 a0 = *(half8*)(&As[(wrow + l31) * 72      + ks * 16 + lhi * 8]);
      half8 a1 = *(half8*)(&As[(wrow + 32 + l31) * 72 + ks * 16 + lhi * 8]);
      half8 b0 = *(half8*)(&Bs[(wcol + l31) * 72      + ks * 16 + lhi * 8]);
      half8 b1 = *(half8*)(&Bs[(wcol + 32 + l31) * 72 + ks * 16 + lhi * 8]);
      acc[0][0] = __builtin_amdgcn_mfma_f32_32x32x16_f16(a0, b0, acc[0][0], 0, 0, 0);
      acc[0][1] = __builtin_amdgcn_mfma_f32_32x32x16_f16(a0, b1, acc[0][1], 0, 0, 0);
      acc[1][0] = __builtin_amdgcn_mfma_f32_32x32x16_f16(a1, b0, acc[1][0], 0, 0, 0);
      acc[1][1] = __builtin_amdgcn_mfma_f32_32x32x16_f16(a1, b1, acc[1][1], 0, 0, 0);
    }
    __syncthreads();
  }
#pragma unroll
  for (int mr = 0; mr < 2; ++mr)
#pragma unroll
    for (int r = 0; r < 16; ++r) {
      int row = row0 + wrow + mr * 32 + (r & 3) + 8 * (r >> 2) + 4 * lhi;
      if (row < M) {
#pragma unroll
        for (int nr = 0; nr < 2; ++nr)
          H[(size_t)row * HID + wcol + nr * 32 + l31] = (_Float16)acc[mr][nr][r];
      }
    }
}

// ---------------- el/er from f16 h ----------------
__global__ __launch_bounds__(256) void k_elr(const _Float16* __restrict__ h,
                                             const float* __restrict__ al,
                                             const float* __restrict__ ar,
                                             float* __restrict__ el,
                                             float* __restrict__ er, int N) {
  int g = blockIdx.x * blockDim.x + threadIdx.x;
  int v = g >> 6, lane = g & 63;
  if (v >= N) return;
  float h0 = (float)h[(size_t)v * HID + lane];
  float h1 = (float)h[(size_t)v * HID + 64 + lane];
  float sl = h0 * al[lane] + h1 * al[64 + lane];
  float sr = h0 * ar[lane] + h1 * ar[64 + lane];
  sl = warp_sum(sl);
  sr = warp_sum(sr);
  if (lane == 0) { el[v] = sl; er[v] = sr; }
}

// ---------------- CSR build ----------------
__global__ void k_hist(const int* __restrict__ dst, int* counts, int E) {
  int i = blockIdx.x * blockDim.x + threadIdx.x;
  if (i < E) atomicAdd(&counts[dst[i]], 1);
}

__global__ __launch_bounds__(256) void k_scan1(const int* __restrict__ counts, int* bsum, int N) {
  __shared__ int s[256];
  int b = blockIdx.x, t = threadIdx.x;
  int i0 = b * 512 + t * 2;
  int v = 0;
  if (i0 < N) v += counts[i0];
  if (i0 + 1 < N) v += counts[i0 + 1];
  s[t] = v;
  __syncthreads();
  for (int off = 128; off > 0; off >>= 1) {
    if (t < off) s[t] += s[t + off];
    __syncthreads();
  }
  if (t == 0) bsum[b] = s[0];
}

__global__ __launch_bounds__(256) void k_scan2(const int* __restrict__ bsum, int* boff, int nblk) {
  __shared__ int s[256];
  int t = threadIdx.x;
  int v = (t < nblk) ? bsum[t] : 0;
  s[t] = v;
  __syncthreads();
#pragma unroll
  for (int off = 1; off < 256; off <<= 1) {
    int u = 0;
    if (t >= off) u = s[t - off];
    __syncthreads();
    s[t] += u;
    __syncthreads();
  }
  if (t < nblk) boff[t] = s[t] - v;
}

__global__ __launch_bounds__(256) void k_scan3(const int* __restrict__ counts,
                                               const int* __restrict__ boff,
                                               int* rowptr, int* cursor, int N) {
  __shared__ int s[256];
  int b = blockIdx.x, t = threadIdx.x;
  int i0 = b * 512 + t * 2;
  int c0 = (i0 < N) ? counts[i0] : 0;
  int c1 = (i0 + 1 < N) ? counts[i0 + 1] : 0;
  int tsum = c0 + c1;
  s[t] = tsum;
  __syncthreads();
#pragma unroll
  for (int off = 1; off < 256; off <<= 1) {
    int u = 0;
    if (t >= off) u = s[t - off];
    __syncthreads();
    s[t] += u;
    __syncthreads();
  }
  int base = boff[b] + s[t] - tsum;
  if (i0 < N)     { rowptr[i0] = base;          cursor[i0] = base; }
  if (i0 + 1 < N) { rowptr[i0 + 1] = base + c0; cursor[i0 + 1] = base + c0; }
}

__global__ void k_fill(const int* __restrict__ src, const int* __restrict__ dst,
                       int* cursor, int* colsrc, int E) {
  int i = blockIdx.x * blockDim.x + threadIdx.x;
  if (i < E) {
    int d = dst[i];
    int pos = atomicAdd(&cursor[d], 1);
    colsrc[pos] = src[i];
  }
}

// ---------------- single-pass edge softmax + aggregation + elu -> eh(f16) ----------------
__global__ __launch_bounds__(256) void k_agg(const _Float16* __restrict__ h,
                                             const float* __restrict__ el,
                                             const float* __restrict__ er,
                                             const int* __restrict__ rowptr,
                                             const int* __restrict__ counts,
                                             const int* __restrict__ colsrc,
                                             const float* __restrict__ bias,
                                             _Float16* __restrict__ eh, int N) {
  int g = blockIdx.x * blockDim.x + threadIdx.x;
  int v = g >> 6, lane = g & 63;
  if (v >= N) return;
  int start = rowptr[v], deg = counts[v];
  float erv = er[v];

  float a0 = 0.f, a1 = 0.f, den = 0.f;
  for (int j = 0; j < deg; ++j) {
    int u = colsrc[start + j];
    float e = el[u] + erv;
    e = (e > 0.f) ? e : LRELU_SLOPE * e;
    float w = expf(e);                  // softmax shift-invariant; e bounded (~<=10)
    den += w;
    a0 = fmaf(w, (float)h[(size_t)u * HID + lane], a0);
    a1 = fmaf(w, (float)h[(size_t)u * HID + 64 + lane], a1);
  }
  float inv = 1.f / den;
  float x0 = a0 * inv + bias[lane];
  float x1 = a1 * inv + bias[64 + lane];
  eh[(size_t)v * HID + lane]      = (_Float16)((x0 > 0.f) ? x0 : expm1f(x0));
  eh[(size_t)v * HID + 64 + lane] = (_Float16)((x1 > 0.f) ? x1 : expm1f(x1));
}

// ---------------- GEMM2: embed = eh @ W_enc  (M x 128)(128 x 64), MFMA ----------------
// block 128x64, BK=128 (single step), 4 waves 2x2, wave 64x32
__global__ __launch_bounds__(256) void k_gemm2(const _Float16* __restrict__ A,
                                               const _Float16* __restrict__ Bt,
                                               float* __restrict__ C,
                                               _Float16* __restrict__ C16, int M) {
  __shared__ _Float16 As[128 * 136];
  __shared__ _Float16 Bs[64 * 136];
  const int tid = threadIdx.x;
  const int lane = tid & 63, wid = tid >> 6;
  const int wrow = (wid >> 1) * 64, wcol = (wid & 1) * 32;
  const int row0 = blockIdx.x * 128;
  const int l31 = lane & 31, lhi = lane >> 5;

#pragma unroll
  for (int c = 0; c < 8; ++c) {         // A: 128 rows x 16 octets
    int idx = tid + c * 256;
    int r = idx >> 4, ko = idx & 15;
    int gr = row0 + r;
    half8 hv = {};
    if (gr < M) hv = *(const half8*)(A + (size_t)gr * HID + ko * 8);
    *(half8*)(&As[r * 136 + ko * 8]) = hv;
  }
#pragma unroll
  for (int c = 0; c < 4; ++c) {         // B: 64 cols x 16 octets
    int idx = tid + c * 256;
    int col = idx >> 4, ko = idx & 15;
    *(half8*)(&Bs[col * 136 + ko * 8]) = *(const half8*)(Bt + (size_t)col * HID + ko * 8);
  }
  __syncthreads();

  f32x16 acc[2] = {};
#pragma unroll
  for (int ks = 0; ks < 8; ++ks) {
    half8 a0 = *(half8*)(&As[(wrow + l31) * 136      + ks * 16 + lhi * 8]);
    half8 a1 = *(half8*)(&As[(wrow + 32 + l31) * 136 + ks * 16 + lhi * 8]);
    half8 b0 = *(half8*)(&Bs[(wcol + l31) * 136      + ks * 16 + lhi * 8]);
    acc[0] = __builtin_amdgcn_mfma_f32_32x32x16_f16(a0, b0, acc[0], 0, 0, 0);
    acc[1] = __builtin_amdgcn_mfma_f32_32x32x16_f16(a1, b0, acc[1], 0, 0, 0);
  }
#pragma unroll
  for (int mr = 0; mr < 2; ++mr)
#pragma unroll
    for (int r = 0; r < 16; ++r) {
      int row = row0 + wrow + mr * 32 + (r & 3) + 8 * (r >> 2) + 4 * lhi;
      if (row < M) {
        int col = wcol + l31;
        float x = acc[mr][r];
        C[(size_t)row * OUTD + col] = x;
        C16[(size_t)row * OUTD + col] = (_Float16)x;
      }
    }
}

// ---------------- GEMM3: pred = elu(embed @ W_dec)  (M x 64)(64 x 512), MFMA ----------------
// block 128x512, BK=64 (single step), 8 waves 2x4, wave 64x128
__global__ __launch_bounds__(512) void k_gemm3(const _Float16* __restrict__ A,
                                               const _Float16* __restrict__ Bt,
                                               float* __restrict__ C, int M) {
  __shared__ _Float16 As[128 * 72];
  __shared__ _Float16 Bs[512 * 72];
  const int tid = threadIdx.x;
  const int lane = tid & 63, wid = tid >> 6;
  const int wrow = (wid >> 2) * 64, wcol = (wid & 3) * 128;
  const int row0 = blockIdx.x * 128;
  const int l31 = lane & 31, lhi = lane >> 5;

#pragma unroll
  for (int c = 0; c < 2; ++c) {         // A: 128 rows x 8 octets
    int idx = tid + c * 512;
    int r = idx >> 3, ko = idx & 7;
    int gr = row0 + r;
    half8 hv = {};
    if (gr < M) hv = *(const half8*)(A + (size_t)gr * OUTD + ko * 8);
    *(half8*)(&As[r * 72 + ko * 8]) = hv;
  }
#pragma unroll
  for (int c = 0; c < 8; ++c) {         // B: 512 cols x 8 octets
    int idx = tid + c * 512;
    int col = idx >> 3, ko = idx & 7;
    *(half8*)(&Bs[col * 72 + ko * 8]) = *(const half8*)(Bt + (size_t)col * OUTD + ko * 8);
  }
  __syncthreads();

  f32x16 acc[2][4] = {};
#pragma unroll
  for (int ks = 0; ks < 4; ++ks) {
    half8 a0 = *(half8*)(&As[(wrow + l31) * 72      + ks * 16 + lhi * 8]);
    half8 a1 = *(half8*)(&As[(wrow + 32 + l31) * 72 + ks * 16 + lhi * 8]);
#pragma unroll
    for (int nr = 0; nr < 4; ++nr) {
      half8 b = *(half8*)(&Bs[(wcol + nr * 32 + l31) * 72 + ks * 16 + lhi * 8]);
      acc[0][nr] = __builtin_amdgcn_mfma_f32_32x32x16_f16(a0, b, acc[0][nr], 0, 0, 0);
      acc[1][nr] = __builtin_amdgcn_mfma_f32_32x32x16_f16(a1, b, acc[1][nr], 0, 0, 0);
    }
  }
#pragma unroll
  for (int mr = 0; mr < 2; ++mr)
#pragma unroll
    for (int r = 0; r < 16; ++r) {
      int row = row0 + wrow + mr * 32 + (r & 3) + 8 * (r >> 2) + 4 * lhi;
      if (row < M) {
#pragma unroll
        for (int nr = 0; nr < 4; ++nr) {
          float x = acc[mr][nr][r];
          C[(size_t)row * IN + wcol + nr * 32 + l31] = (x > 0.f) ? x : expm1f(x);
        }
      }
    }
}

// ---------------- DEC soft assignment q: one THREAD per node, no cross-lane ----------------
__global__ __launch_bounds__(256) void k_q(const float* __restrict__ embed,
                                           const float* __restrict__ cent,
                                           float* __restrict__ q, int N) {
  __shared__ float Cs[KC * OUTD];       // natural layout [k][d]
  int tid = threadIdx.x;
#pragma unroll
  for (int t = 0; t < 5; ++t) {
    int i = tid + t * 256;
    if (i < KC * OUTD) Cs[i] = cent[i];
  }
  __syncthreads();
  int v = blockIdx.x * 256 + tid;
  if (v >= N) return;

  const float* erow = embed + (size_t)v * OUTD;
  float acc[KC];
#pragma unroll
  for (int k = 0; k < KC; ++k) acc[k] = 0.f;

#pragma unroll
  for (int d0 = 0; d0 < OUTD; d0 += 4) {
    float4 e4 = *(const float4*)(erow + d0);
#pragma unroll
    for (int k = 0; k < KC; ++k) {
      float4 c4 = *(const float4*)(&Cs[k * OUTD + d0]);   // wave-uniform broadcast
      float dx = e4.x - c4.x, dy = e4.y - c4.y, dz = e4.z - c4.z, dw = e4.w - c4.w;
      acc[k] = fmaf(dx, dx, fmaf(dy, dy, fmaf(dz, dz, fmaf(dw, dw, acc[k]))));
    }
  }
  float qs = 0.f;
#pragma unroll
  for (int k = 0; k < KC; ++k) {
    acc[k] = 1.f / (1.f + acc[k] + 1e-8f);
    qs += acc[k];
  }
  float inv = 1.f / qs;
  float* qrow = q + (size_t)v * KC;
#pragma unroll
  for (int k0 = 0; k0 < KC; k0 += 4) {
    float4 o = make_float4(acc[k0] * inv, acc[k0 + 1] * inv, acc[k0 + 2] * inv, acc[k0 + 3] * inv);
    *(float4*)(qrow + k0) = o;   // 80B row pitch is 16B-aligned
  }
}

static inline size_t align16(size_t x) { return (x + 15) & ~(size_t)15; }

extern "C" void kernel_launch(void* const* d_in, const int* in_sizes, int n_in,
                              void* d_out, int out_size, void* d_ws, size_t ws_size,
                              hipStream_t stream) {
  const float* x      = (const float*)d_in[0];
  const float* W_gat  = (const float*)d_in[1];
  const float* attn_l = (const float*)d_in[2];
  const float* attn_r = (const float*)d_in[3];
  const float* bias   = (const float*)d_in[4];
  const float* W_enc  = (const float*)d_in[5];
  const float* W_dec  = (const float*)d_in[6];
  const float* cent   = (const float*)d_in[7];
  const int*   src    = (const int*)d_in[8];
  const int*   dst    = (const int*)d_in[9];

  const int N = in_sizes[0] / IN;
  const int E = in_sizes[8];

  float* out   = (float*)d_out;
  float* embed = out;                            // N x 64
  float* pred  = out + (size_t)N * OUTD;         // N x 512
  float* qout  = pred + (size_t)N * IN;          // N x 20

  char* w = (char*)d_ws;
  size_t off = 0;
  _Float16* h16   = (_Float16*)(w + off); off = align16(off + sizeof(_Float16) * (size_t)N * HID);
  _Float16* eh16  = (_Float16*)(w + off); off = align16(off + sizeof(_Float16) * (size_t)N * HID);
  _Float16* emb16 = (_Float16*)(w + off); off = align16(off + sizeof(_Float16) * (size_t)N * OUTD);
  float* el       = (float*)(w + off);    off = align16(off + sizeof(float) * (size_t)N);
  float* er       = (float*)(w + off);    off = align16(off + sizeof(float) * (size_t)N);
  _Float16* Bt_g  = (_Float16*)(w + off); off = align16(off + sizeof(_Float16) * HID * IN);
  _Float16* Bt_e  = (_Float16*)(w + off); off = align16(off + sizeof(_Float16) * OUTD * HID);
  _Float16* Bt_d  = (_Float16*)(w + off); off = align16(off + sizeof(_Float16) * IN * OUTD);
  int* counts     = (int*)(w + off);      off = align16(off + sizeof(int) * (size_t)N);
  int* rowptr     = (int*)(w + off);      off = align16(off + sizeof(int) * (size_t)(N + 1));
  int* cursor     = (int*)(w + off);      off = align16(off + sizeof(int) * (size_t)N);
  int* colsrc     = (int*)(w + off);      off = align16(off + sizeof(int) * (size_t)E);
  int* bsum       = (int*)(w + off);      off = align16(off + sizeof(int) * 256);
  int* boff       = (int*)(w + off);      off = align16(off + sizeof(int) * 256);

  const int nblk_scan = (N + 511) / 512;
  const int prep_elems = HID * IN + OUTD * HID + IN * OUTD;

  hipLaunchKernelGGL(k_prepB, dim3((prep_elems + 255) / 256), dim3(256), 0, stream,
                     W_gat, W_enc, W_dec, Bt_g, Bt_e, Bt_d);
  hipLaunchKernelGGL(k_zero_int, dim3((N + 255) / 256), dim3(256), 0, stream, counts, N);
  hipLaunchKernelGGL(k_gemm1, dim3((N + 127) / 128), dim3(256), 0, stream, x, Bt_g, h16, N);
  hipLaunchKernelGGL(k_elr, dim3(((size_t)N * 64 + 255) / 256), dim3(256), 0, stream,
                     h16, attn_l, attn_r, el, er, N);
  hipLaunchKernelGGL(k_hist, dim3((E + 255) / 256), dim3(256), 0, stream, dst, counts, E);
  hipLaunchKernelGGL(k_scan1, dim3(nblk_scan), dim3(256), 0, stream, counts, bsum, N);
  hipLaunchKernelGGL(k_scan2, dim3(1), dim3(256), 0, stream, bsum, boff, nblk_scan);
  hipLaunchKernelGGL(k_scan3, dim3(nblk_scan), dim3(256), 0, stream, counts, boff, rowptr, cursor, N);
  hipLaunchKernelGGL(k_fill, dim3((E + 255) / 256), dim3(256), 0, stream, src, dst, cursor, colsrc, E);
  hipLaunchKernelGGL(k_agg, dim3(((size_t)N * 64 + 255) / 256), dim3(256), 0, stream,
                     h16, el, er, rowptr, counts, colsrc, bias, eh16, N);
  hipLaunchKernelGGL(k_gemm2, dim3((N + 127) / 128), dim3(256), 0, stream, eh16, Bt_e, embed, emb16, N);
  hipLaunchKernelGGL(k_gemm3, dim3((N + 127) / 128), dim3(512), 0, stream, emb16, Bt_d, pred, N);
  hipLaunchKernelGGL(k_q, dim3((N + 255) / 256), dim3(256), 0, stream, embed, cent, qout, N);
}

// Round 4
// 340.146 us; speedup vs baseline: 2.1215x; 1.1515x over previous
//
#include <hip/hip_runtime.h>
#include <math.h>

constexpr int IN   = 512;
constexpr int HID  = 128;
constexpr int OUTD = 64;
constexpr int KC   = 20;
#define LRELU_SLOPE 0.2f

typedef _Float16 half8 __attribute__((ext_vector_type(8)));
typedef _Float16 half2v __attribute__((ext_vector_type(2)));
typedef float f32x16 __attribute__((ext_vector_type(16)));

__device__ __forceinline__ float warp_sum(float v) {
#pragma unroll
  for (int o = 32; o > 0; o >>= 1) v += __shfl_xor(v, o, 64);
  return v;
}

// ---------------- prep: transpose+convert weights to f16 [col][K]; zero counts ----------------
__global__ __launch_bounds__(256) void k_prep(const float* __restrict__ Wg,
                                              const float* __restrict__ We,
                                              const float* __restrict__ Wd,
                                              _Float16* Bg, _Float16* Be, _Float16* Bd,
                                              int* counts, int N) {
  int i = blockIdx.x * 256 + threadIdx.x;
  if (i < N) counts[i] = 0;
  if (i < HID * IN) {                 // Bg[c][k] = Wg[k][c], c<128,k<512
    int c = i >> 9, k = i & 511;
    Bg[i] = (_Float16)Wg[(size_t)k * HID + c];
    return;
  }
  i -= HID * IN;
  if (i < OUTD * HID) {               // Be[c][k] = We[k][c], c<64,k<128
    int c = i >> 7, k = i & 127;
    Be[i] = (_Float16)We[(size_t)k * OUTD + c];
    return;
  }
  i -= OUTD * HID;
  if (i < IN * OUTD) {                // Bd[c][k] = Wd[k][c], c<512,k<64
    int c = i >> 6, k = i & 63;
    Bd[i] = (_Float16)Wd[(size_t)k * IN + c];
  }
}

// ---------------- GEMM1: h(f16) = x @ W_gat   (M x 512)(512 x 128), MFMA ----------------
// block 128x128, BK=64, 4 waves in 2x2, wave tile 64x64 (2x2 of 32x32x16)
__global__ __launch_bounds__(256) void k_gemm1(const float* __restrict__ A,
                                               const _Float16* __restrict__ Bt,
                                               _Float16* __restrict__ H, int M) {
  __shared__ _Float16 As[128 * 72];
  __shared__ _Float16 Bs[128 * 72];
  const int tid = threadIdx.x;
  const int lane = tid & 63, wid = tid >> 6;
  const int wrow = (wid >> 1) * 64, wcol = (wid & 1) * 64;
  const int row0 = blockIdx.x * 128;
  const int l31 = lane & 31, lhi = lane >> 5;

  f32x16 acc[2][2] = {};

  for (int k0 = 0; k0 < IN; k0 += 64) {
#pragma unroll
    for (int c = 0; c < 4; ++c) {       // A: 128 rows x 8 k-octets
      int idx = tid + c * 256;
      int r = idx >> 3, ko = idx & 7;
      int gr = row0 + r;
      float4 v0 = make_float4(0.f, 0.f, 0.f, 0.f), v1 = v0;
      if (gr < M) {
        const float* p = A + (size_t)gr * IN + k0 + ko * 8;
        v0 = *(const float4*)p;
        v1 = *(const float4*)(p + 4);
      }
      half8 hv;
      hv[0] = (_Float16)v0.x; hv[1] = (_Float16)v0.y; hv[2] = (_Float16)v0.z; hv[3] = (_Float16)v0.w;
      hv[4] = (_Float16)v1.x; hv[5] = (_Float16)v1.y; hv[6] = (_Float16)v1.z; hv[7] = (_Float16)v1.w;
      *(half8*)(&As[r * 72 + ko * 8]) = hv;
    }
#pragma unroll
    for (int c = 0; c < 4; ++c) {       // B: 128 cols x 8 k-octets (already f16, [col][K])
      int idx = tid + c * 256;
      int col = idx >> 3, ko = idx & 7;
      *(half8*)(&Bs[col * 72 + ko * 8]) = *(const half8*)(Bt + (size_t)col * IN + k0 + ko * 8);
    }
    __syncthreads();
#pragma unroll
    for (int ks = 0; ks < 4; ++ks) {
      half8 a0 = *(half8*)(&As[(wrow + l31) * 72      + ks * 16 + lhi * 8]);
      half8 a1 = *(half8*)(&As[(wrow + 32 + l31) * 72 + ks * 16 + lhi * 8]);
      half8 b0 = *(half8*)(&Bs[(wcol + l31) * 72      + ks * 16 + lhi * 8]);
      half8 b1 = *(half8*)(&Bs[(wcol + 32 + l31) * 72 + ks * 16 + lhi * 8]);
      acc[0][0] = __builtin_amdgcn_mfma_f32_32x32x16_f16(a0, b0, acc[0][0], 0, 0, 0);
      acc[0][1] = __builtin_amdgcn_mfma_f32_32x32x16_f16(a0, b1, acc[0][1], 0, 0, 0);
      acc[1][0] = __builtin_amdgcn_mfma_f32_32x32x16_f16(a1, b0, acc[1][0], 0, 0, 0);
      acc[1][1] = __builtin_amdgcn_mfma_f32_32x32x16_f16(a1, b1, acc[1][1], 0, 0, 0);
    }
    __syncthreads();
  }
#pragma unroll
  for (int mr = 0; mr < 2; ++mr)
#pragma unroll
    for (int r = 0; r < 16; ++r) {
      int row = row0 + wrow + mr * 32 + (r & 3) + 8 * (r >> 2) + 4 * lhi;
      if (row < M) {
#pragma unroll
        for (int nr = 0; nr < 2; ++nr)
          H[(size_t)row * HID + wcol + nr * 32 + l31] = (_Float16)acc[mr][nr][r];
      }
    }
}

// ---------------- el/er from f16 h ----------------
__global__ __launch_bounds__(256) void k_elr(const _Float16* __restrict__ h,
                                             const float* __restrict__ al,
                                             const float* __restrict__ ar,
                                             float* __restrict__ el,
                                             float* __restrict__ er, int N) {
  int g = blockIdx.x * blockDim.x + threadIdx.x;
  int v = g >> 6, lane = g & 63;
  if (v >= N) return;
  float h0 = (float)h[(size_t)v * HID + lane];
  float h1 = (float)h[(size_t)v * HID + 64 + lane];
  float sl = h0 * al[lane] + h1 * al[64 + lane];
  float sr = h0 * ar[lane] + h1 * ar[64 + lane];
  sl = warp_sum(sl);
  sr = warp_sum(sr);
  if (lane == 0) { el[v] = sl; er[v] = sr; }
}

// ---------------- CSR build ----------------
__global__ void k_hist(const int* __restrict__ dst, int* counts, int E) {
  int i = blockIdx.x * blockDim.x + threadIdx.x;
  if (i < E) atomicAdd(&counts[dst[i]], 1);
}

__global__ __launch_bounds__(256) void k_scan1(const int* __restrict__ counts, int* bsum, int N) {
  __shared__ int s[256];
  int b = blockIdx.x, t = threadIdx.x;
  int i0 = b * 512 + t * 2;
  int v = 0;
  if (i0 < N) v += counts[i0];
  if (i0 + 1 < N) v += counts[i0 + 1];
  s[t] = v;
  __syncthreads();
  for (int off = 128; off > 0; off >>= 1) {
    if (t < off) s[t] += s[t + off];
    __syncthreads();
  }
  if (t == 0) bsum[b] = s[0];
}

__global__ __launch_bounds__(256) void k_scan2(const int* __restrict__ bsum, int* boff, int nblk) {
  __shared__ int s[256];
  int t = threadIdx.x;
  int v = (t < nblk) ? bsum[t] : 0;
  s[t] = v;
  __syncthreads();
#pragma unroll
  for (int off = 1; off < 256; off <<= 1) {
    int u = 0;
    if (t >= off) u = s[t - off];
    __syncthreads();
    s[t] += u;
    __syncthreads();
  }
  if (t < nblk) boff[t] = s[t] - v;
}

__global__ __launch_bounds__(256) void k_scan3(const int* __restrict__ counts,
                                               const int* __restrict__ boff,
                                               int* rowptr, int* cursor, int N) {
  __shared__ int s[256];
  int b = blockIdx.x, t = threadIdx.x;
  int i0 = b * 512 + t * 2;
  int c0 = (i0 < N) ? counts[i0] : 0;
  int c1 = (i0 + 1 < N) ? counts[i0 + 1] : 0;
  int tsum = c0 + c1;
  s[t] = tsum;
  __syncthreads();
#pragma unroll
  for (int off = 1; off < 256; off <<= 1) {
    int u = 0;
    if (t >= off) u = s[t - off];
    __syncthreads();
    s[t] += u;
    __syncthreads();
  }
  int base = boff[b] + s[t] - tsum;
  if (i0 < N)     { rowptr[i0] = base;          cursor[i0] = base; }
  if (i0 + 1 < N) { rowptr[i0 + 1] = base + c0; cursor[i0 + 1] = base + c0; }
}

__global__ void k_fill(const int* __restrict__ src, const int* __restrict__ dst,
                       int* cursor, int* colsrc, int E) {
  int i = blockIdx.x * blockDim.x + threadIdx.x;
  if (i < E) {
    int d = dst[i];
    int pos = atomicAdd(&cursor[d], 1);
    colsrc[pos] = src[i];
  }
}

// ---------------- single-pass edge softmax + aggregation + elu -> eh(f16) ----------------
// half2 gathers (1 dword/lane/edge), 2-edge unroll for independent load chains
__global__ __launch_bounds__(256) void k_agg(const _Float16* __restrict__ h,
                                             const float* __restrict__ el,
                                             const float* __restrict__ er,
                                             const int* __restrict__ rowptr,
                                             const int* __restrict__ counts,
                                             const int* __restrict__ colsrc,
                                             const float* __restrict__ bias,
                                             _Float16* __restrict__ eh, int N) {
  int g = blockIdx.x * blockDim.x + threadIdx.x;
  int v = g >> 6, lane = g & 63;
  if (v >= N) return;
  int start = rowptr[v], deg = counts[v];
  float erv = er[v];

  float a0 = 0.f, a1 = 0.f, den0 = 0.f;
  float c0 = 0.f, c1 = 0.f, den1 = 0.f;
  int j = 0;
  for (; j + 2 <= deg; j += 2) {
    int u0 = colsrc[start + j];
    int u1 = colsrc[start + j + 1];
    float e0 = el[u0] + erv; e0 = (e0 > 0.f) ? e0 : LRELU_SLOPE * e0;
    float e1 = el[u1] + erv; e1 = (e1 > 0.f) ? e1 : LRELU_SLOPE * e1;
    float w0 = expf(e0), w1 = expf(e1);
    half2v h0 = *(const half2v*)(h + (size_t)u0 * HID + 2 * lane);
    half2v h1 = *(const half2v*)(h + (size_t)u1 * HID + 2 * lane);
    den0 += w0; den1 += w1;
    a0 = fmaf(w0, (float)h0[0], a0); a1 = fmaf(w0, (float)h0[1], a1);
    c0 = fmaf(w1, (float)h1[0], c0); c1 = fmaf(w1, (float)h1[1], c1);
  }
  if (j < deg) {
    int u0 = colsrc[start + j];
    float e0 = el[u0] + erv; e0 = (e0 > 0.f) ? e0 : LRELU_SLOPE * e0;
    float w0 = expf(e0);
    half2v h0 = *(const half2v*)(h + (size_t)u0 * HID + 2 * lane);
    den0 += w0;
    a0 = fmaf(w0, (float)h0[0], a0); a1 = fmaf(w0, (float)h0[1], a1);
  }
  a0 += c0; a1 += c1; den0 += den1;
  float inv = 1.f / den0;
  float x0 = a0 * inv + bias[2 * lane];
  float x1 = a1 * inv + bias[2 * lane + 1];
  half2v o;
  o[0] = (_Float16)((x0 > 0.f) ? x0 : expm1f(x0));
  o[1] = (_Float16)((x1 > 0.f) ? x1 : expm1f(x1));
  *(half2v*)(eh + (size_t)v * HID + 2 * lane) = o;
}

// ---------------- GEMM2: embed = eh @ W_enc  (M x 128)(128 x 64), MFMA ----------------
// block 128x64, BK=128 (single step), 4 waves 2x2, wave 64x32
__global__ __launch_bounds__(256) void k_gemm2(const _Float16* __restrict__ A,
                                               const _Float16* __restrict__ Bt,
                                               float* __restrict__ C,
                                               _Float16* __restrict__ C16, int M) {
  __shared__ _Float16 As[128 * 136];
  __shared__ _Float16 Bs[64 * 136];
  const int tid = threadIdx.x;
  const int lane = tid & 63, wid = tid >> 6;
  const int wrow = (wid >> 1) * 64, wcol = (wid & 1) * 32;
  const int row0 = blockIdx.x * 128;
  const int l31 = lane & 31, lhi = lane >> 5;

#pragma unroll
  for (int c = 0; c < 8; ++c) {         // A: 128 rows x 16 octets
    int idx = tid + c * 256;
    int r = idx >> 4, ko = idx & 15;
    int gr = row0 + r;
    half8 hv = {};
    if (gr < M) hv = *(const half8*)(A + (size_t)gr * HID + ko * 8);
    *(half8*)(&As[r * 136 + ko * 8]) = hv;
  }
#pragma unroll
  for (int c = 0; c < 4; ++c) {         // B: 64 cols x 16 octets
    int idx = tid + c * 256;
    int col = idx >> 4, ko = idx & 15;
    *(half8*)(&Bs[col * 136 + ko * 8]) = *(const half8*)(Bt + (size_t)col * HID + ko * 8);
  }
  __syncthreads();

  f32x16 acc[2] = {};
#pragma unroll
  for (int ks = 0; ks < 8; ++ks) {
    half8 a0 = *(half8*)(&As[(wrow + l31) * 136      + ks * 16 + lhi * 8]);
    half8 a1 = *(half8*)(&As[(wrow + 32 + l31) * 136 + ks * 16 + lhi * 8]);
    half8 b0 = *(half8*)(&Bs[(wcol + l31) * 136      + ks * 16 + lhi * 8]);
    acc[0] = __builtin_amdgcn_mfma_f32_32x32x16_f16(a0, b0, acc[0], 0, 0, 0);
    acc[1] = __builtin_amdgcn_mfma_f32_32x32x16_f16(a1, b0, acc[1], 0, 0, 0);
  }
#pragma unroll
  for (int mr = 0; mr < 2; ++mr)
#pragma unroll
    for (int r = 0; r < 16; ++r) {
      int row = row0 + wrow + mr * 32 + (r & 3) + 8 * (r >> 2) + 4 * lhi;
      if (row < M) {
        int col = wcol + l31;
        float x = acc[mr][r];
        C[(size_t)row * OUTD + col] = x;
        C16[(size_t)row * OUTD + col] = (_Float16)x;
      }
    }
}

// ---------------- GEMM3: pred = elu(embed @ W_dec)  (M x 64)(64 x 512), MFMA ----------------
// block 128 rows x 256 cols (grid.y=2), BK=64 single step, 8 waves 2x4, wave 64x64
__global__ __launch_bounds__(512) void k_gemm3(const _Float16* __restrict__ A,
                                               const _Float16* __restrict__ Bt,
                                               float* __restrict__ C, int M) {
  __shared__ _Float16 As[128 * 72];
  __shared__ _Float16 Bs[256 * 72];
  const int tid = threadIdx.x;
  const int lane = tid & 63, wid = tid >> 6;
  const int wrow = (wid >> 2) * 64, wcol = (wid & 3) * 64;
  const int row0 = blockIdx.x * 128;
  const int cb = blockIdx.y * 256;
  const int l31 = lane & 31, lhi = lane >> 5;

#pragma unroll
  for (int c = 0; c < 2; ++c) {         // A: 128 rows x 8 octets = 1024 slots
    int idx = tid + c * 512;
    int r = idx >> 3, ko = idx & 7;
    int gr = row0 + r;
    half8 hv = {};
    if (gr < M) hv = *(const half8*)(A + (size_t)gr * OUTD + ko * 8);
    *(half8*)(&As[r * 72 + ko * 8]) = hv;
  }
#pragma unroll
  for (int c = 0; c < 4; ++c) {         // B: 256 cols x 8 octets = 2048 slots
    int idx = tid + c * 512;
    int col = idx >> 3, ko = idx & 7;
    *(half8*)(&Bs[col * 72 + ko * 8]) = *(const half8*)(Bt + (size_t)(cb + col) * OUTD + ko * 8);
  }
  __syncthreads();

  f32x16 acc[2][2] = {};
#pragma unroll
  for (int ks = 0; ks < 4; ++ks) {
    half8 a0 = *(half8*)(&As[(wrow + l31) * 72      + ks * 16 + lhi * 8]);
    half8 a1 = *(half8*)(&As[(wrow + 32 + l31) * 72 + ks * 16 + lhi * 8]);
    half8 b0 = *(half8*)(&Bs[(wcol + l31) * 72      + ks * 16 + lhi * 8]);
    half8 b1 = *(half8*)(&Bs[(wcol + 32 + l31) * 72 + ks * 16 + lhi * 8]);
    acc[0][0] = __builtin_amdgcn_mfma_f32_32x32x16_f16(a0, b0, acc[0][0], 0, 0, 0);
    acc[0][1] = __builtin_amdgcn_mfma_f32_32x32x16_f16(a0, b1, acc[0][1], 0, 0, 0);
    acc[1][0] = __builtin_amdgcn_mfma_f32_32x32x16_f16(a1, b0, acc[1][0], 0, 0, 0);
    acc[1][1] = __builtin_amdgcn_mfma_f32_32x32x16_f16(a1, b1, acc[1][1], 0, 0, 0);
  }
#pragma unroll
  for (int mr = 0; mr < 2; ++mr)
#pragma unroll
    for (int r = 0; r < 16; ++r) {
      int row = row0 + wrow + mr * 32 + (r & 3) + 8 * (r >> 2) + 4 * lhi;
      if (row < M) {
#pragma unroll
        for (int nr = 0; nr < 2; ++nr) {
          float x = acc[mr][nr][r];
          C[(size_t)row * IN + cb + wcol + nr * 32 + l31] = (x > 0.f) ? x : expm1f(x);
        }
      }
    }
}

// ---------------- DEC soft assignment q: one THREAD per node, no cross-lane ----------------
__global__ __launch_bounds__(256) void k_q(const float* __restrict__ embed,
                                           const float* __restrict__ cent,
                                           float* __restrict__ q, int N) {
  __shared__ float Cs[KC * OUTD];       // natural layout [k][d]
  int tid = threadIdx.x;
#pragma unroll
  for (int t = 0; t < 5; ++t) {
    int i = tid + t * 256;
    if (i < KC * OUTD) Cs[i] = cent[i];
  }
  __syncthreads();
  int v = blockIdx.x * 256 + tid;
  if (v >= N) return;

  const float* erow = embed + (size_t)v * OUTD;
  float acc[KC];
#pragma unroll
  for (int k = 0; k < KC; ++k) acc[k] = 0.f;

#pragma unroll
  for (int d0 = 0; d0 < OUTD; d0 += 4) {
    float4 e4 = *(const float4*)(erow + d0);
#pragma unroll
    for (int k = 0; k < KC; ++k) {
      float4 c4 = *(const float4*)(&Cs[k * OUTD + d0]);   // wave-uniform broadcast
      float dx = e4.x - c4.x, dy = e4.y - c4.y, dz = e4.z - c4.z, dw = e4.w - c4.w;
      acc[k] = fmaf(dx, dx, fmaf(dy, dy, fmaf(dz, dz, fmaf(dw, dw, acc[k]))));
    }
  }
  float qs = 0.f;
#pragma unroll
  for (int k = 0; k < KC; ++k) {
    acc[k] = 1.f / (1.f + acc[k] + 1e-8f);
    qs += acc[k];
  }
  float inv = 1.f / qs;
  float* qrow = q + (size_t)v * KC;
#pragma unroll
  for (int k0 = 0; k0 < KC; k0 += 4) {
    float4 o = make_float4(acc[k0] * inv, acc[k0 + 1] * inv, acc[k0 + 2] * inv, acc[k0 + 3] * inv);
    *(float4*)(qrow + k0) = o;   // 80B row pitch is 16B-aligned
  }
}

static inline size_t align16(size_t x) { return (x + 15) & ~(size_t)15; }

extern "C" void kernel_launch(void* const* d_in, const int* in_sizes, int n_in,
                              void* d_out, int out_size, void* d_ws, size_t ws_size,
                              hipStream_t stream) {
  const float* x      = (const float*)d_in[0];
  const float* W_gat  = (const float*)d_in[1];
  const float* attn_l = (const float*)d_in[2];
  const float* attn_r = (const float*)d_in[3];
  const float* bias   = (const float*)d_in[4];
  const float* W_enc  = (const float*)d_in[5];
  const float* W_dec  = (const float*)d_in[6];
  const float* cent   = (const float*)d_in[7];
  const int*   src    = (const int*)d_in[8];
  const int*   dst    = (const int*)d_in[9];

  const int N = in_sizes[0] / IN;
  const int E = in_sizes[8];

  float* out   = (float*)d_out;
  float* embed = out;                            // N x 64
  float* pred  = out + (size_t)N * OUTD;         // N x 512
  float* qout  = pred + (size_t)N * IN;          // N x 20

  char* w = (char*)d_ws;
  size_t off = 0;
  _Float16* h16   = (_Float16*)(w + off); off = align16(off + sizeof(_Float16) * (size_t)N * HID);
  _Float16* eh16  = (_Float16*)(w + off); off = align16(off + sizeof(_Float16) * (size_t)N * HID);
  _Float16* emb16 = (_Float16*)(w + off); off = align16(off + sizeof(_Float16) * (size_t)N * OUTD);
  float* el       = (float*)(w + off);    off = align16(off + sizeof(float) * (size_t)N);
  float* er       = (float*)(w + off);    off = align16(off + sizeof(float) * (size_t)N);
  _Float16* Bt_g  = (_Float16*)(w + off); off = align16(off + sizeof(_Float16) * HID * IN);
  _Float16* Bt_e  = (_Float16*)(w + off); off = align16(off + sizeof(_Float16) * OUTD * HID);
  _Float16* Bt_d  = (_Float16*)(w + off); off = align16(off + sizeof(_Float16) * IN * OUTD);
  int* counts     = (int*)(w + off);      off = align16(off + sizeof(int) * (size_t)N);
  int* rowptr     = (int*)(w + off);      off = align16(off + sizeof(int) * (size_t)(N + 1));
  int* cursor     = (int*)(w + off);      off = align16(off + sizeof(int) * (size_t)N);
  int* colsrc     = (int*)(w + off);      off = align16(off + sizeof(int) * (size_t)E);
  int* bsum       = (int*)(w + off);      off = align16(off + sizeof(int) * 256);
  int* boff       = (int*)(w + off);      off = align16(off + sizeof(int) * 256);

  const int nblk_scan = (N + 511) / 512;
  const int prep_elems = HID * IN + OUTD * HID + IN * OUTD;   // 106496 > N
  const int nblk_prep = (prep_elems > N ? prep_elems : N);

  hipLaunchKernelGGL(k_prep, dim3((nblk_prep + 255) / 256), dim3(256), 0, stream,
                     W_gat, W_enc, W_dec, Bt_g, Bt_e, Bt_d, counts, N);
  hipLaunchKernelGGL(k_gemm1, dim3((N + 127) / 128), dim3(256), 0, stream, x, Bt_g, h16, N);
  hipLaunchKernelGGL(k_elr, dim3(((size_t)N * 64 + 255) / 256), dim3(256), 0, stream,
                     h16, attn_l, attn_r, el, er, N);
  hipLaunchKernelGGL(k_hist, dim3((E + 255) / 256), dim3(256), 0, stream, dst, counts, E);
  hipLaunchKernelGGL(k_scan1, dim3(nblk_scan), dim3(256), 0, stream, counts, bsum, N);
  hipLaunchKernelGGL(k_scan2, dim3(1), dim3(256), 0, stream, bsum, boff, nblk_scan);
  hipLaunchKernelGGL(k_scan3, dim3(nblk_scan), dim3(256), 0, stream, counts, boff, rowptr, cursor, N);
  hipLaunchKernelGGL(k_fill, dim3((E + 255) / 256), dim3(256), 0, stream, src, dst, cursor, colsrc, E);
  hipLaunchKernelGGL(k_agg, dim3(((size_t)N * 64 + 255) / 256), dim3(256), 0, stream,
                     h16, el, er, rowptr, counts, colsrc, bias, eh16, N);
  hipLaunchKernelGGL(k_gemm2, dim3((N + 127) / 128), dim3(256), 0, stream, eh16, Bt_e, embed, emb16, N);
  hipLaunchKernelGGL(k_gemm3, dim3((N + 127) / 128, 2), dim3(512), 0, stream, emb16, Bt_d, pred, N);
  hipLaunchKernelGGL(k_q, dim3((N + 255) / 256), dim3(256), 0, stream, embed, cent, qout, N);
}

// Round 5
// 329.058 us; speedup vs baseline: 2.1930x; 1.0337x over previous
//
#include <hip/hip_runtime.h>
#include <math.h>

constexpr int IN   = 512;
constexpr int HID  = 128;
constexpr int OUTD = 64;
constexpr int KC   = 20;
#define LRELU_SLOPE 0.2f

typedef _Float16 half8 __attribute__((ext_vector_type(8)));
typedef _Float16 half2v __attribute__((ext_vector_type(2)));
typedef float f32x16 __attribute__((ext_vector_type(16)));

__device__ __forceinline__ float warp_sum(float v) {
#pragma unroll
  for (int o = 32; o > 0; o >>= 1) v += __shfl_xor(v, o, 64);
  return v;
}

// ---------------- prep: transpose+convert weights to f16 [col][K]; zero counts ----------------
__global__ __launch_bounds__(256) void k_prep(const float* __restrict__ Wg,
                                              const float* __restrict__ We,
                                              const float* __restrict__ Wd,
                                              _Float16* Bg, _Float16* Be, _Float16* Bd,
                                              int* counts, int N) {
  int i = blockIdx.x * 256 + threadIdx.x;
  if (i < N) counts[i] = 0;
  if (i < HID * IN) {                 // Bg[c][k] = Wg[k][c], c<128,k<512
    int c = i >> 9, k = i & 511;
    Bg[i] = (_Float16)Wg[(size_t)k * HID + c];
    return;
  }
  i -= HID * IN;
  if (i < OUTD * HID) {               // Be[c][k] = We[k][c], c<64,k<128
    int c = i >> 7, k = i & 127;
    Be[i] = (_Float16)We[(size_t)k * OUTD + c];
    return;
  }
  i -= OUTD * HID;
  if (i < IN * OUTD) {                // Bd[c][k] = Wd[k][c], c<512,k<64
    int c = i >> 6, k = i & 63;
    Bd[i] = (_Float16)Wd[(size_t)k * IN + c];
  }
}

// ---------------- GEMM1: h(f16) = x @ W_gat   (M x 512)(512 x 128), MFMA ----------------
// block 128x128, BK=64, 4 waves in 2x2, wave tile 64x64 (2x2 of 32x32x16)
__global__ __launch_bounds__(256) void k_gemm1(const float* __restrict__ A,
                                               const _Float16* __restrict__ Bt,
                                               _Float16* __restrict__ H, int M) {
  __shared__ _Float16 As[128 * 72];
  __shared__ _Float16 Bs[128 * 72];
  const int tid = threadIdx.x;
  const int lane = tid & 63, wid = tid >> 6;
  const int wrow = (wid >> 1) * 64, wcol = (wid & 1) * 64;
  const int row0 = blockIdx.x * 128;
  const int l31 = lane & 31, lhi = lane >> 5;

  f32x16 acc[2][2] = {};

  for (int k0 = 0; k0 < IN; k0 += 64) {
#pragma unroll
    for (int c = 0; c < 4; ++c) {       // A: 128 rows x 8 k-octets
      int idx = tid + c * 256;
      int r = idx >> 3, ko = idx & 7;
      int gr = row0 + r;
      float4 v0 = make_float4(0.f, 0.f, 0.f, 0.f), v1 = v0;
      if (gr < M) {
        const float* p = A + (size_t)gr * IN + k0 + ko * 8;
        v0 = *(const float4*)p;
        v1 = *(const float4*)(p + 4);
      }
      half8 hv;
      hv[0] = (_Float16)v0.x; hv[1] = (_Float16)v0.y; hv[2] = (_Float16)v0.z; hv[3] = (_Float16)v0.w;
      hv[4] = (_Float16)v1.x; hv[5] = (_Float16)v1.y; hv[6] = (_Float16)v1.z; hv[7] = (_Float16)v1.w;
      *(half8*)(&As[r * 72 + ko * 8]) = hv;
    }
#pragma unroll
    for (int c = 0; c < 4; ++c) {       // B: 128 cols x 8 k-octets (already f16, [col][K])
      int idx = tid + c * 256;
      int col = idx >> 3, ko = idx & 7;
      *(half8*)(&Bs[col * 72 + ko * 8]) = *(const half8*)(Bt + (size_t)col * IN + k0 + ko * 8);
    }
    __syncthreads();
#pragma unroll
    for (int ks = 0; ks < 4; ++ks) {
      half8 a0 = *(half8*)(&As[(wrow + l31) * 72      + ks * 16 + lhi * 8]);
      half8 a1 = *(half8*)(&As[(wrow + 32 + l31) * 72 + ks * 16 + lhi * 8]);
      half8 b0 = *(half8*)(&Bs[(wcol + l31) * 72      + ks * 16 + lhi * 8]);
      half8 b1 = *(half8*)(&Bs[(wcol + 32 + l31) * 72 + ks * 16 + lhi * 8]);
      acc[0][0] = __builtin_amdgcn_mfma_f32_32x32x16_f16(a0, b0, acc[0][0], 0, 0, 0);
      acc[0][1] = __builtin_amdgcn_mfma_f32_32x32x16_f16(a0, b1, acc[0][1], 0, 0, 0);
      acc[1][0] = __builtin_amdgcn_mfma_f32_32x32x16_f16(a1, b0, acc[1][0], 0, 0, 0);
      acc[1][1] = __builtin_amdgcn_mfma_f32_32x32x16_f16(a1, b1, acc[1][1], 0, 0, 0);
    }
    __syncthreads();
  }
#pragma unroll
  for (int mr = 0; mr < 2; ++mr)
#pragma unroll
    for (int r = 0; r < 16; ++r) {
      int row = row0 + wrow + mr * 32 + (r & 3) + 8 * (r >> 2) + 4 * lhi;
      if (row < M) {
#pragma unroll
        for (int nr = 0; nr < 2; ++nr)
          H[(size_t)row * HID + wcol + nr * 32 + l31] = (_Float16)acc[mr][nr][r];
      }
    }
}

// ---------------- el/er from f16 h ----------------
__global__ __launch_bounds__(256) void k_elr(const _Float16* __restrict__ h,
                                             const float* __restrict__ al,
                                             const float* __restrict__ ar,
                                             float* __restrict__ el,
                                             float* __restrict__ er, int N) {
  int g = blockIdx.x * blockDim.x + threadIdx.x;
  int v = g >> 6, lane = g & 63;
  if (v >= N) return;
  float h0 = (float)h[(size_t)v * HID + lane];
  float h1 = (float)h[(size_t)v * HID + 64 + lane];
  float sl = h0 * al[lane] + h1 * al[64 + lane];
  float sr = h0 * ar[lane] + h1 * ar[64 + lane];
  sl = warp_sum(sl);
  sr = warp_sum(sr);
  if (lane == 0) { el[v] = sl; er[v] = sr; }
}

// ---------------- CSR build ----------------
__global__ void k_hist(const int* __restrict__ dst, int* counts, int E) {
  int i = blockIdx.x * blockDim.x + threadIdx.x;
  if (i < E) atomicAdd(&counts[dst[i]], 1);
}

__global__ __launch_bounds__(256) void k_scan1(const int* __restrict__ counts, int* bsum, int N) {
  __shared__ int s[256];
  int b = blockIdx.x, t = threadIdx.x;
  int i0 = b * 512 + t * 2;
  int v = 0;
  if (i0 < N) v += counts[i0];
  if (i0 + 1 < N) v += counts[i0 + 1];
  s[t] = v;
  __syncthreads();
  for (int off = 128; off > 0; off >>= 1) {
    if (t < off) s[t] += s[t + off];
    __syncthreads();
  }
  if (t == 0) bsum[b] = s[0];
}

__global__ __launch_bounds__(256) void k_scan2(const int* __restrict__ bsum, int* boff, int nblk) {
  __shared__ int s[256];
  int t = threadIdx.x;
  int v = (t < nblk) ? bsum[t] : 0;
  s[t] = v;
  __syncthreads();
#pragma unroll
  for (int off = 1; off < 256; off <<= 1) {
    int u = 0;
    if (t >= off) u = s[t - off];
    __syncthreads();
    s[t] += u;
    __syncthreads();
  }
  if (t < nblk) boff[t] = s[t] - v;
}

__global__ __launch_bounds__(256) void k_scan3(const int* __restrict__ counts,
                                               const int* __restrict__ boff,
                                               int* rowptr, int* cursor, int N) {
  __shared__ int s[256];
  int b = blockIdx.x, t = threadIdx.x;
  int i0 = b * 512 + t * 2;
  int c0 = (i0 < N) ? counts[i0] : 0;
  int c1 = (i0 + 1 < N) ? counts[i0 + 1] : 0;
  int tsum = c0 + c1;
  s[t] = tsum;
  __syncthreads();
#pragma unroll
  for (int off = 1; off < 256; off <<= 1) {
    int u = 0;
    if (t >= off) u = s[t - off];
    __syncthreads();
    s[t] += u;
    __syncthreads();
  }
  int base = boff[b] + s[t] - tsum;
  if (i0 < N)     { rowptr[i0] = base;          cursor[i0] = base; }
  if (i0 + 1 < N) { rowptr[i0 + 1] = base + c0; cursor[i0 + 1] = base + c0; }
}

__global__ void k_fill(const int* __restrict__ src, const int* __restrict__ dst,
                       int* cursor, int* colsrc, int E) {
  int i = blockIdx.x * blockDim.x + threadIdx.x;
  if (i < E) {
    int d = dst[i];
    int pos = atomicAdd(&cursor[d], 1);
    colsrc[pos] = src[i];
  }
}

// ---------------- edge softmax + aggregation + elu -> eh(f16) ----------------
// Phase 1: lanes 0..cnt-1 compute per-edge (u, w) in parallel (one load pass).
// Phase 2: 4-deep batched h gathers via shuffle-broadcast of (u, w).
__global__ __launch_bounds__(256) void k_agg(const _Float16* __restrict__ h,
                                             const float* __restrict__ el,
                                             const float* __restrict__ er,
                                             const int* __restrict__ rowptr,
                                             const int* __restrict__ counts,
                                             const int* __restrict__ colsrc,
                                             const float* __restrict__ bias,
                                             _Float16* __restrict__ eh, int N) {
  int g = blockIdx.x * blockDim.x + threadIdx.x;
  int v = g >> 6, lane = g & 63;
  if (v >= N) return;
  int start = rowptr[v], deg = counts[v];
  float erv = er[v];

  float a0 = 0.f, a1 = 0.f, den = 0.f;
  for (int base = 0; base < deg; base += 64) {
    int cnt = deg - base; if (cnt > 64) cnt = 64;
    int u_l = 0; float w_l = 0.f;
    if (lane < cnt) {
      u_l = colsrc[start + base + lane];
      float e = el[u_l] + erv;
      e = (e > 0.f) ? e : LRELU_SLOPE * e;
      w_l = __expf(e);                  // softmax shift-invariant; e bounded
    }
    den += warp_sum(w_l);
    int cntR = (cnt + 3) & ~3;
    for (int j = 0; j < cntR; j += 4) { // lanes >= cnt carry w=0, u=0 (harmless)
      int   u0 = __shfl(u_l, j, 64),     u1 = __shfl(u_l, j + 1, 64);
      int   u2 = __shfl(u_l, j + 2, 64), u3 = __shfl(u_l, j + 3, 64);
      float w0 = __shfl(w_l, j, 64),     w1 = __shfl(w_l, j + 1, 64);
      float w2 = __shfl(w_l, j + 2, 64), w3 = __shfl(w_l, j + 3, 64);
      half2v h0 = *(const half2v*)(h + (size_t)u0 * HID + 2 * lane);
      half2v h1 = *(const half2v*)(h + (size_t)u1 * HID + 2 * lane);
      half2v h2 = *(const half2v*)(h + (size_t)u2 * HID + 2 * lane);
      half2v h3 = *(const half2v*)(h + (size_t)u3 * HID + 2 * lane);
      a0 = fmaf(w0, (float)h0[0], a0); a1 = fmaf(w0, (float)h0[1], a1);
      a0 = fmaf(w1, (float)h1[0], a0); a1 = fmaf(w1, (float)h1[1], a1);
      a0 = fmaf(w2, (float)h2[0], a0); a1 = fmaf(w2, (float)h2[1], a1);
      a0 = fmaf(w3, (float)h3[0], a0); a1 = fmaf(w3, (float)h3[1], a1);
    }
  }
  float inv = 1.f / den;
  float x0 = a0 * inv + bias[2 * lane];
  float x1 = a1 * inv + bias[2 * lane + 1];
  half2v o;
  o[0] = (_Float16)((x0 > 0.f) ? x0 : expm1f(x0));
  o[1] = (_Float16)((x1 > 0.f) ? x1 : expm1f(x1));
  *(half2v*)(eh + (size_t)v * HID + 2 * lane) = o;
}

// ---------------- GEMM2 + q: embed = eh @ W_enc, then DEC assignment ----------------
// block 128x64 (full embed rows), 4 waves 2x2; q epilogue reuses As as f32 [128][68]
__global__ __launch_bounds__(256) void k_gemm2q(const _Float16* __restrict__ A,
                                                const _Float16* __restrict__ Bt,
                                                const float* __restrict__ cent,
                                                float* __restrict__ C,
                                                _Float16* __restrict__ C16,
                                                float* __restrict__ q, int M) {
  __shared__ _Float16 As[128 * 136];   // 34816 B; reused as f32 [128][68] (exact fit)
  __shared__ _Float16 Bs[64 * 136];    // 17408 B; reused as f32 cent [20][64] (5120 B)
  const int tid = threadIdx.x;
  const int lane = tid & 63, wid = tid >> 6;
  const int wrow = (wid >> 1) * 64, wcol = (wid & 1) * 32;
  const int row0 = blockIdx.x * 128;
  const int l31 = lane & 31, lhi = lane >> 5;

#pragma unroll
  for (int c = 0; c < 8; ++c) {         // A: 128 rows x 16 octets
    int idx = tid + c * 256;
    int r = idx >> 4, ko = idx & 15;
    int gr = row0 + r;
    half8 hv = {};
    if (gr < M) hv = *(const half8*)(A + (size_t)gr * HID + ko * 8);
    *(half8*)(&As[r * 136 + ko * 8]) = hv;
  }
#pragma unroll
  for (int c = 0; c < 4; ++c) {         // B: 64 cols x 16 octets
    int idx = tid + c * 256;
    int col = idx >> 4, ko = idx & 15;
    *(half8*)(&Bs[col * 136 + ko * 8]) = *(const half8*)(Bt + (size_t)col * HID + ko * 8);
  }
  __syncthreads();

  f32x16 acc[2] = {};
#pragma unroll
  for (int ks = 0; ks < 8; ++ks) {
    half8 a0 = *(half8*)(&As[(wrow + l31) * 136      + ks * 16 + lhi * 8]);
    half8 a1 = *(half8*)(&As[(wrow + 32 + l31) * 136 + ks * 16 + lhi * 8]);
    half8 b0 = *(half8*)(&Bs[(wcol + l31) * 136      + ks * 16 + lhi * 8]);
    acc[0] = __builtin_amdgcn_mfma_f32_32x32x16_f16(a0, b0, acc[0], 0, 0, 0);
    acc[1] = __builtin_amdgcn_mfma_f32_32x32x16_f16(a1, b0, acc[1], 0, 0, 0);
  }
  __syncthreads();                      // As/Bs ds_reads done; safe to repurpose

  float* Es = (float*)As;               // [128][68]
  float* Cs = (float*)Bs;               // [20][64]
#pragma unroll
  for (int t = 0; t < 5; ++t) {
    int i = tid + t * 256;
    if (i < KC * OUTD) Cs[i] = cent[i];
  }
#pragma unroll
  for (int mr = 0; mr < 2; ++mr)
#pragma unroll
    for (int r = 0; r < 16; ++r) {
      int lr = wrow + mr * 32 + (r & 3) + 8 * (r >> 2) + 4 * lhi;
      int row = row0 + lr;
      int col = wcol + l31;
      float x = acc[mr][r];
      Es[lr * 68 + col] = x;
      if (row < M) {
        C[(size_t)row * OUTD + col] = x;
        C16[(size_t)row * OUTD + col] = (_Float16)x;
      }
    }
  __syncthreads();

  if (tid < 128) {
    int row = row0 + tid;
    if (row < M) {
      const float* erow = &Es[tid * 68];
      float accq[KC];
#pragma unroll
      for (int k = 0; k < KC; ++k) accq[k] = 0.f;
#pragma unroll
      for (int d0 = 0; d0 < OUTD; d0 += 4) {
        float4 e4 = *(const float4*)(erow + d0);
#pragma unroll
        for (int k = 0; k < KC; ++k) {
          float4 c4 = *(const float4*)(&Cs[k * OUTD + d0]);   // wave-uniform broadcast
          float dx = e4.x - c4.x, dy = e4.y - c4.y, dz = e4.z - c4.z, dw = e4.w - c4.w;
          accq[k] = fmaf(dx, dx, fmaf(dy, dy, fmaf(dz, dz, fmaf(dw, dw, accq[k]))));
        }
      }
      float qs = 0.f;
#pragma unroll
      for (int k = 0; k < KC; ++k) {
        accq[k] = 1.f / (1.f + accq[k] + 1e-8f);
        qs += accq[k];
      }
      float inv = 1.f / qs;
      float* qrow = q + (size_t)row * KC;
#pragma unroll
      for (int k0 = 0; k0 < KC; k0 += 4) {
        float4 o = make_float4(accq[k0] * inv, accq[k0 + 1] * inv,
                               accq[k0 + 2] * inv, accq[k0 + 3] * inv);
        *(float4*)(qrow + k0) = o;
      }
    }
  }
}

// ---------------- GEMM3: pred = elu(embed @ W_dec)  (M x 64)(64 x 512), MFMA ----------------
// block 128 rows x 128 cols (grid.y=4), 4 waves 2x2, wave 64x64; 36KB LDS -> 4 blocks/CU
__global__ __launch_bounds__(256) void k_gemm3(const _Float16* __restrict__ A,
                                               const _Float16* __restrict__ Bt,
                                               float* __restrict__ C, int M) {
  __shared__ _Float16 As[128 * 72];
  __shared__ _Float16 Bs[128 * 72];
  const int tid = threadIdx.x;
  const int lane = tid & 63, wid = tid >> 6;
  const int wrow = (wid >> 1) * 64, wcol = (wid & 1) * 64;
  const int row0 = blockIdx.x * 128;
  const int cb = blockIdx.y * 128;
  const int l31 = lane & 31, lhi = lane >> 5;

#pragma unroll
  for (int c = 0; c < 4; ++c) {         // A: 128 rows x 8 octets = 1024 slots
    int idx = tid + c * 256;
    int r = idx >> 3, ko = idx & 7;
    int gr = row0 + r;
    half8 hv = {};
    if (gr < M) hv = *(const half8*)(A + (size_t)gr * OUTD + ko * 8);
    *(half8*)(&As[r * 72 + ko * 8]) = hv;
  }
#pragma unroll
  for (int c = 0; c < 4; ++c) {         // B: 128 cols x 8 octets = 1024 slots
    int idx = tid + c * 256;
    int col = idx >> 3, ko = idx & 7;
    *(half8*)(&Bs[col * 72 + ko * 8]) = *(const half8*)(Bt + (size_t)(cb + col) * OUTD + ko * 8);
  }
  __syncthreads();

  f32x16 acc[2][2] = {};
#pragma unroll
  for (int ks = 0; ks < 4; ++ks) {
    half8 a0 = *(half8*)(&As[(wrow + l31) * 72      + ks * 16 + lhi * 8]);
    half8 a1 = *(half8*)(&As[(wrow + 32 + l31) * 72 + ks * 16 + lhi * 8]);
    half8 b0 = *(half8*)(&Bs[(wcol + l31) * 72      + ks * 16 + lhi * 8]);
    half8 b1 = *(half8*)(&Bs[(wcol + 32 + l31) * 72 + ks * 16 + lhi * 8]);
    acc[0][0] = __builtin_amdgcn_mfma_f32_32x32x16_f16(a0, b0, acc[0][0], 0, 0, 0);
    acc[0][1] = __builtin_amdgcn_mfma_f32_32x32x16_f16(a0, b1, acc[0][1], 0, 0, 0);
    acc[1][0] = __builtin_amdgcn_mfma_f32_32x32x16_f16(a1, b0, acc[1][0], 0, 0, 0);
    acc[1][1] = __builtin_amdgcn_mfma_f32_32x32x16_f16(a1, b1, acc[1][1], 0, 0, 0);
  }
#pragma unroll
  for (int mr = 0; mr < 2; ++mr)
#pragma unroll
    for (int r = 0; r < 16; ++r) {
      int row = row0 + wrow + mr * 32 + (r & 3) + 8 * (r >> 2) + 4 * lhi;
      if (row < M) {
#pragma unroll
        for (int nr = 0; nr < 2; ++nr) {
          float x = acc[mr][nr][r];
          C[(size_t)row * IN + cb + wcol + nr * 32 + l31] = (x > 0.f) ? x : expm1f(x);
        }
      }
    }
}

static inline size_t align16(size_t x) { return (x + 15) & ~(size_t)15; }

extern "C" void kernel_launch(void* const* d_in, const int* in_sizes, int n_in,
                              void* d_out, int out_size, void* d_ws, size_t ws_size,
                              hipStream_t stream) {
  const float* x      = (const float*)d_in[0];
  const float* W_gat  = (const float*)d_in[1];
  const float* attn_l = (const float*)d_in[2];
  const float* attn_r = (const float*)d_in[3];
  const float* bias   = (const float*)d_in[4];
  const float* W_enc  = (const float*)d_in[5];
  const float* W_dec  = (const float*)d_in[6];
  const float* cent   = (const float*)d_in[7];
  const int*   src    = (const int*)d_in[8];
  const int*   dst    = (const int*)d_in[9];

  const int N = in_sizes[0] / IN;
  const int E = in_sizes[8];

  float* out   = (float*)d_out;
  float* embed = out;                            // N x 64
  float* pred  = out + (size_t)N * OUTD;         // N x 512
  float* qout  = pred + (size_t)N * IN;          // N x 20

  char* w = (char*)d_ws;
  size_t off = 0;
  _Float16* h16   = (_Float16*)(w + off); off = align16(off + sizeof(_Float16) * (size_t)N * HID);
  _Float16* eh16  = (_Float16*)(w + off); off = align16(off + sizeof(_Float16) * (size_t)N * HID);
  _Float16* emb16 = (_Float16*)(w + off); off = align16(off + sizeof(_Float16) * (size_t)N * OUTD);
  float* el       = (float*)(w + off);    off = align16(off + sizeof(float) * (size_t)N);
  float* er       = (float*)(w + off);    off = align16(off + sizeof(float) * (size_t)N);
  _Float16* Bt_g  = (_Float16*)(w + off); off = align16(off + sizeof(_Float16) * HID * IN);
  _Float16* Bt_e  = (_Float16*)(w + off); off = align16(off + sizeof(_Float16) * OUTD * HID);
  _Float16* Bt_d  = (_Float16*)(w + off); off = align16(off + sizeof(_Float16) * IN * OUTD);
  int* counts     = (int*)(w + off);      off = align16(off + sizeof(int) * (size_t)N);
  int* rowptr     = (int*)(w + off);      off = align16(off + sizeof(int) * (size_t)(N + 1));
  int* cursor     = (int*)(w + off);      off = align16(off + sizeof(int) * (size_t)N);
  int* colsrc     = (int*)(w + off);      off = align16(off + sizeof(int) * (size_t)E);
  int* bsum       = (int*)(w + off);      off = align16(off + sizeof(int) * 256);
  int* boff       = (int*)(w + off);      off = align16(off + sizeof(int) * 256);

  const int nblk_scan = (N + 511) / 512;
  const int prep_elems = HID * IN + OUTD * HID + IN * OUTD;   // 106496 > N
  const int nblk_prep = (prep_elems > N ? prep_elems : N);

  hipLaunchKernelGGL(k_prep, dim3((nblk_prep + 255) / 256), dim3(256), 0, stream,
                     W_gat, W_enc, W_dec, Bt_g, Bt_e, Bt_d, counts, N);
  hipLaunchKernelGGL(k_gemm1, dim3((N + 127) / 128), dim3(256), 0, stream, x, Bt_g, h16, N);
  hipLaunchKernelGGL(k_elr, dim3(((size_t)N * 64 + 255) / 256), dim3(256), 0, stream,
                     h16, attn_l, attn_r, el, er, N);
  hipLaunchKernelGGL(k_hist, dim3((E + 255) / 256), dim3(256), 0, stream, dst, counts, E);
  hipLaunchKernelGGL(k_scan1, dim3(nblk_scan), dim3(256), 0, stream, counts, bsum, N);
  hipLaunchKernelGGL(k_scan2, dim3(1), dim3(256), 0, stream, bsum, boff, nblk_scan);
  hipLaunchKernelGGL(k_scan3, dim3(nblk_scan), dim3(256), 0, stream, counts, boff, rowptr, cursor, N);
  hipLaunchKernelGGL(k_fill, dim3((E + 255) / 256), dim3(256), 0, stream, src, dst, cursor, colsrc, E);
  hipLaunchKernelGGL(k_agg, dim3(((size_t)N * 64 + 255) / 256), dim3(256), 0, stream,
                     h16, el, er, rowptr, counts, colsrc, bias, eh16, N);
  hipLaunchKernelGGL(k_gemm2q, dim3((N + 127) / 128), dim3(256), 0, stream,
                     eh16, Bt_e, cent, embed, emb16, qout, N);
  hipLaunchKernelGGL(k_gemm3, dim3((N + 127) / 128, 4), dim3(256), 0, stream, emb16, Bt_d, pred, N);
}